// Round 13
// baseline (766.233 us; speedup 1.0000x reference)
//
#include <hip/hip_runtime.h>
#include <hip/hip_bf16.h>
#include <math.h>

// Problem dims
#define BQ 8
#define SQ 512
#define HID 768
#define NH 12
#define DH 64
#define INTER 3072
#define NL 4
#define M_TOK (BQ*SQ)   // 4096 tokens

typedef unsigned short ushort_t;
typedef __attribute__((ext_vector_type(8))) short bf16x8;
typedef __attribute__((ext_vector_type(8))) unsigned short u16x8;
typedef __attribute__((ext_vector_type(4))) float f32x4;

__device__ __forceinline__ float bf2f(ushort_t u) {
  union { float f; unsigned int i; } v; v.i = ((unsigned int)u) << 16; return v.f;
}
__device__ __forceinline__ ushort_t f2bf(float f) {
  __hip_bfloat16 h = __float2bfloat16(f);
  return *reinterpret_cast<ushort_t*>(&h);
}

__device__ __forceinline__ void gload_lds16(const ushort_t* g, ushort_t* l) {
  __builtin_amdgcn_global_load_lds(
      (const __attribute__((address_space(1))) void*)g,
      (__attribute__((address_space(3))) void*)l, 16, 0, 0);
}

template<int N>
__device__ __forceinline__ void wait_vm() {
  if constexpr (N == 0)      asm volatile("s_waitcnt vmcnt(0)" ::: "memory");
  else if constexpr (N == 6) asm volatile("s_waitcnt vmcnt(6)" ::: "memory");
  else if constexpr (N == 8) asm volatile("s_waitcnt vmcnt(8)" ::: "memory");
  else                       asm volatile("s_waitcnt vmcnt(12)" ::: "memory");
}

// ---------------------------------------------------------------------------
// prep: maskf, maskbias, hb = bf16(hidden*mask)
// ---------------------------------------------------------------------------
__global__ __launch_bounds__(256) void prep_kernel(
    const float* __restrict__ hidden, const float* __restrict__ amask,
    float* __restrict__ maskf, float* __restrict__ maskbias,
    ushort_t* __restrict__ hb)
{
  int i = blockIdx.x * 256 + threadIdx.x;
  if (i < M_TOK * HID) {
    float m = amask[i / HID];
    hb[i] = f2bf(hidden[i] * m);
    if (i < M_TOK) {
      maskf[i] = amask[i];
      maskbias[i] = (1.0f - amask[i]) * (-10000.0f);
    }
  }
}

// ---------------------------------------------------------------------------
// KERPLE bias tables for ALL layers: kbt_all[l][h][d]
// ---------------------------------------------------------------------------
__global__ void kerple_all_kernel(const float* __restrict__ r1,
                                  const float* __restrict__ r2,
                                  const float* __restrict__ r3,
                                  float* __restrict__ kbt_all)
{
  int lh = blockIdx.x;        // l*NH + h
  int d  = threadIdx.x;
  float c1 = fmaxf(r1[lh], 1e-7f);
  float c2 = fmaxf(r2[lh], 1e-7f);
  float c3 = fmaxf(r3[lh], 1e-7f);
  float v = 0.0f;
  if (d > 0) v = -c1 * log1pf(c2 * powf((float)d, c3));
  kbt_all[lh * SQ + d] = v;
}

// ---------------------------------------------------------------------------
// per-layer weight cast fp32 -> bf16, all 4 weight blocks in one launch.
// ---------------------------------------------------------------------------
#define WS0 (3*HID*HID)
#define WS1 (HID*HID)
#define WS2 (2*INTER*HID)
#define WS3 (HID*INTER)
#define WTOT (WS0+WS1+WS2+WS3)

__global__ __launch_bounds__(256) void wcast_layer_kernel(
    const float* __restrict__ w0, const float* __restrict__ w1,
    const float* __restrict__ w2, const float* __restrict__ w3,
    ushort_t* __restrict__ dst)
{
  int i = (blockIdx.x * 256 + threadIdx.x) * 4;
  if (i >= WTOT) return;
  const float* src; int off;
  if (i < WS0)                { src = w0; off = i; }
  else if (i < WS0+WS1)       { src = w1; off = i - WS0; }
  else if (i < WS0+WS1+WS2)   { src = w2; off = i - WS0 - WS1; }
  else                        { src = w3; off = i - WS0 - WS1 - WS2; }
  float4 v = *reinterpret_cast<const float4*>(src + off);
  ushort4 o;
  o.x = f2bf(v.x); o.y = f2bf(v.y); o.z = f2bf(v.z); o.w = f2bf(v.w);
  *reinterpret_cast<ushort4*>(dst + i) = o;
}

// ---------------------------------------------------------------------------
// bf16 MFMA GEMM. DB=1: counted-vmcnt double-buffer. DB=0: single-buffer.
// WPB = __launch_bounds__ min-waves-per-EU (occupancy request; 4 for GLU:
// 128-reg budget fits acc 64 AGPR + 64 VGPR exactly, LDS 40KB -> 4 blocks/CU).
// QKV: MF=4 DB=1 (r12 post-mortem: MF=2 doubled B staging traffic, -14us/layer).
// GLU: MF=2 NB=2 DB=0 (r12: occupancy 18->31% = 92->69us).
// Block decode: plain blockIdx (r10: linear dispatch already XCD-partitions bn).
// LDS XOR-swizzle at 16B-chunk granularity keyed on (row>>SSH)&SMK, both sides.
// ---------------------------------------------------------------------------
template<int MF, int NB, int BK, int EPI, int VN, int DB, int WPB>
__global__ __launch_bounds__(256, WPB) void mfma_gemm(
    const ushort_t* __restrict__ A, const ushort_t* __restrict__ B0p,
    const ushort_t* __restrict__ B1p, const float* __restrict__ bias,
    const float* __restrict__ rowscale, ushort_t* __restrict__ Cb,
    int N, int K)
{
  constexpr int BM   = MF * 32;
  constexpr int SMK  = BK / 8 - 1;            // swizzle mask (7 or 3)
  constexpr int SSH  = (BK == 32) ? 1 : 0;    // swizzle row shift
  constexpr int AIS  = (BM * BK * 2) / 4096;  // gload issues per wave, A tile
  constexpr int BIS  = (128 * BK * 2) / 4096; // per B tensor
  constexpr int KH   = BK / 32;
  constexpr int NBUF = DB ? 2 : 1;

  __shared__ ushort_t As_[NBUF][BM * BK];
  __shared__ ushort_t Bs_[NBUF][NB][128 * BK];

  int tid = threadIdx.x;
  int lane = tid & 63, w = tid >> 6;
  int wr = w >> 1, wc = w & 1;
  int g = lane >> 4, r = lane & 15;
  int bn = blockIdx.x, bm = blockIdx.y;

  f32x4 acc[NB][MF][4];
#pragma unroll
  for (int p = 0; p < NB; ++p)
#pragma unroll
    for (int m = 0; m < MF; ++m)
#pragma unroll
      for (int n = 0; n < 4; ++n) acc[p][m][n] = (f32x4){0.f, 0.f, 0.f, 0.f};

  const ushort_t* Arow  = A   + (size_t)bm * BM * K;
  const ushort_t* Brow0 = B0p + (size_t)bn * 128 * K;
  const ushort_t* Brow1 = (NB == 2) ? (B1p + (size_t)bn * 128 * K) : nullptr;

  // staging: linear LDS dest (wave-uniform base + lane*16), inverse-swizzled
  // global source chunk (involution: lc = pc ^ ((row >> SSH) & SMK)).
  auto stage = [&](const ushort_t* base, ushort_t* lds, int k0, int ISS_w) {
#pragma unroll
    for (int i = 0; i < 4; ++i) {
      if (i >= ISS_w) break;
      int o   = (w * ISS_w + i) * 1024 + lane * 16;  // byte offset in tile
      int row = o / (BK * 2);
      int pc  = (o >> 4) & SMK;
      int lc  = pc ^ ((row >> SSH) & SMK);
      gload_lds16(base + (size_t)row * K + k0 + lc * 8,
                  lds + ((w * ISS_w + i) << 9));
    }
  };
  auto stage_all = [&](int k0, int buf) {
    stage(Arow,  &As_[buf][0],    k0, AIS);
    stage(Brow0, &Bs_[buf][0][0], k0, BIS);
    if constexpr (NB == 2) stage(Brow1, &Bs_[buf][1][0], k0, BIS);
  };
  auto compute = [&](int buf) {
#pragma unroll
    for (int kh = 0; kh < KH; ++kh) {
      bf16x8 af[MF], bf_[4];
#pragma unroll
      for (int m = 0; m < MF; ++m)
        af[m] = *(const bf16x8*)(&As_[buf][(wr * (BM/2) + m * 16 + r) * BK
                  + (((kh * 4 + g) ^ ((r >> SSH) & SMK)) * 8)]);
#pragma unroll
      for (int n = 0; n < 4; ++n)
        bf_[n] = *(const bf16x8*)(&Bs_[buf][0][(wc * 64 + n * 16 + r) * BK
                  + (((kh * 4 + g) ^ ((r >> SSH) & SMK)) * 8)]);
#pragma unroll
      for (int m = 0; m < MF; ++m)
#pragma unroll
        for (int n = 0; n < 4; ++n)
          acc[0][m][n] = __builtin_amdgcn_mfma_f32_16x16x32_bf16(
              af[m], bf_[n], acc[0][m][n], 0, 0, 0);
      if constexpr (NB == 2) {
        bf16x8 bg[4];
#pragma unroll
        for (int n = 0; n < 4; ++n)
          bg[n] = *(const bf16x8*)(&Bs_[buf][1][(wc * 64 + n * 16 + r) * BK
                    + (((kh * 4 + g) ^ ((r >> SSH) & SMK)) * 8)]);
#pragma unroll
        for (int m = 0; m < MF; ++m)
#pragma unroll
          for (int n = 0; n < 4; ++n)
            acc[1][m][n] = __builtin_amdgcn_mfma_f32_16x16x32_bf16(
                af[m], bg[n], acc[1][m][n], 0, 0, 0);
      }
    }
  };

  int NT = K / BK;
  if constexpr (DB) {
    stage_all(0, 0);
    for (int t = 0; t < NT; ++t) {
      int cur = t & 1;
      if (t + 1 < NT) {
        stage_all((t + 1) * BK, cur ^ 1);
        wait_vm<VN>();             // current tile landed; next stays in flight
      } else {
        wait_vm<0>();
      }
      __builtin_amdgcn_s_barrier();
      compute(cur);
      __builtin_amdgcn_s_barrier(); // all reads of buf[cur] retired
    }
  } else {
    for (int t = 0; t < NT; ++t) {
      stage_all(t * BK, 0);
      wait_vm<0>();
      __builtin_amdgcn_s_barrier();
      compute(0);
      __builtin_amdgcn_s_barrier();
    }
  }

  // epilogue: C/D layout col=lane&15, row=(lane>>4)*4+j
  int r0 = bm * BM + wr * (BM/2), c0 = bn * 128 + wc * 64;
#pragma unroll
  for (int m = 0; m < MF; ++m)
#pragma unroll
    for (int n = 0; n < 4; ++n) {
      int col  = c0 + n * 16 + (lane & 15);
      int rowb = r0 + m * 16 + (lane >> 4) * 4;
      if constexpr (EPI == 0) {
        float bv = bias ? bias[col] : 0.0f;
#pragma unroll
        for (int j = 0; j < 4; ++j)
          Cb[(size_t)(rowb + j) * N + col] = f2bf(acc[0][m][n][j] + bv);
      } else if constexpr (EPI == 1) {
#pragma unroll
        for (int j = 0; j < 4; ++j) {
          float va = acc[0][m][n][j];
          float vb = acc[1][m][n][j];
          float ge = 0.5f * va * (1.0f + erff(va * 0.70710678118654752440f));
          Cb[(size_t)(rowb + j) * N + col] = f2bf(ge * vb);
        }
      } else {
        float bv = bias ? bias[col] : 0.0f;
#pragma unroll
        for (int j = 0; j < 4; ++j) {
          float v = (acc[0][m][n][j] + bv) * rowscale[rowb + j];
          Cb[(size_t)(rowb + j) * N + col] = f2bf(v);
        }
      }
    }
}

// ---------------------------------------------------------------------------
// MFMA flash attention + T5 setprio. T1 decode (r10, neutral-to-positive).
// ---------------------------------------------------------------------------
__global__ __launch_bounds__(256) void attn_mfma(
    const ushort_t* __restrict__ qkvb, const float* __restrict__ kbt,
    const float* __restrict__ maskbias, ushort_t* __restrict__ attnb)
{
  __shared__ ushort_t Ks[64 * 64];   // K[k][d]
  __shared__ ushort_t Vt[64 * 64];   // V^T[d][k]
  __shared__ ushort_t Ps[64 * 64];   // P[q][k]
  __shared__ float    kbs[SQ];
  __shared__ float    mbs[SQ];

  int tid  = threadIdx.x;
  int lane = tid & 63, w = tid >> 6;
  int g = lane >> 4, r = lane & 15;
  int bid = blockIdx.x;
  int qt = (bid >> 3) & 7;
  int t_ = (bid & 7) * 12 + (bid >> 6);
  int hh = t_ % NH;
  int b  = t_ / NH;
  int q0 = qt * 64;

  for (int i = tid; i < SQ; i += 256) {
    kbs[i] = kbt[hh * SQ + i];
    mbs[i] = maskbias[b * SQ + i];
  }

  bf16x8 qf[2];
  {
    const ushort_t* qsrc = qkvb + (size_t)(b * SQ + q0 + w * 16 + r) * (3 * HID)
                         + hh * DH + g * 8;
    qf[0] = *(const bf16x8*)(qsrc);
    qf[1] = *(const bf16x8*)(qsrc + 32);
  }

  float m_run[4], l_run[4];
  f32x4 oacc[4];
#pragma unroll
  for (int j = 0; j < 4; ++j) { m_run[j] = -1e30f; l_run[j] = 0.f; }
#pragma unroll
  for (int nd = 0; nd < 4; ++nd) oacc[nd] = (f32x4){0.f, 0.f, 0.f, 0.f};

  int k2 = (tid & 31) * 2, dg = tid >> 5;

  for (int kc = 0; kc < 8; ++kc) {
    __syncthreads();
#pragma unroll
    for (int ii = 0; ii < 2; ++ii) {
      int row = (w * 2 + ii) * 8 + (lane >> 3);
      int c   = lane & 7;
      const ushort_t* src = qkvb + (size_t)(b * SQ + kc * 64 + row) * (3 * HID)
                          + HID + hh * DH + ((c ^ (row & 7)) * 8);
      gload_lds16(src, Ks + (w * 2 + ii) * 512 + lane * 8);
    }
    {
      const ushort_t* v0 = qkvb + (size_t)(b * SQ + kc * 64 + k2) * (3 * HID)
                         + 2 * HID + hh * DH + dg * 8;
      const ushort_t* v1 = v0 + 3 * HID;
      u16x8 a = *(const u16x8*)v0;
      u16x8 c = *(const u16x8*)v1;
#pragma unroll
      for (int u = 0; u < 8; ++u) {
        int d = dg * 8 + u;
        int addr = d * 64 + (((k2 >> 3) ^ (d & 7)) * 8) + (k2 & 7);
        ushort2 pr; pr.x = (ushort_t)a[u]; pr.y = (ushort_t)c[u];
        *(ushort2*)(Vt + addr) = pr;
      }
    }
    __syncthreads();

    f32x4 sacc[4];
#pragma unroll
    for (int n = 0; n < 4; ++n) sacc[n] = (f32x4){0.f, 0.f, 0.f, 0.f};
    __builtin_amdgcn_s_setprio(1);
#pragma unroll
    for (int kh = 0; kh < 2; ++kh) {
#pragma unroll
      for (int n = 0; n < 4; ++n) {
        bf16x8 kf = *(const bf16x8*)(Ks + (n * 16 + r) * 64
                                     + (((g + kh * 4) ^ (r & 7)) * 8));
        sacc[n] = __builtin_amdgcn_mfma_f32_16x16x32_bf16(qf[kh], kf, sacc[n], 0, 0, 0);
      }
    }
    __builtin_amdgcn_s_setprio(0);

    float sval[4][4], mx[4];
#pragma unroll
    for (int j = 0; j < 4; ++j) mx[j] = -1e30f;
#pragma unroll
    for (int n = 0; n < 4; ++n) {
      int kg = kc * 64 + n * 16 + r;
      float mb = mbs[kg];
#pragma unroll
      for (int j = 0; j < 4; ++j) {
        int qg = q0 + w * 16 + g * 4 + j;
        float s = sacc[n][j] * 0.125f + mb + kbs[abs(qg - kg)];
        sval[n][j] = s;
        mx[j] = fmaxf(mx[j], s);
      }
    }
#pragma unroll
    for (int j = 0; j < 4; ++j) {
      mx[j] = fmaxf(mx[j], __shfl_xor(mx[j], 1));
      mx[j] = fmaxf(mx[j], __shfl_xor(mx[j], 2));
      mx[j] = fmaxf(mx[j], __shfl_xor(mx[j], 4));
      mx[j] = fmaxf(mx[j], __shfl_xor(mx[j], 8));
      float mn = fmaxf(m_run[j], mx[j]);
      mx[j] = __expf(m_run[j] - mn);   // reuse as scale
      m_run[j] = mn;
    }
    float rs[4] = {0.f, 0.f, 0.f, 0.f};
#pragma unroll
    for (int n = 0; n < 4; ++n) {
#pragma unroll
      for (int j = 0; j < 4; ++j) {
        float pp = __expf(sval[n][j] - m_run[j]);
        int prow = w * 16 + g * 4 + j;
        int pcol = n * 16 + r;
        Ps[prow * 64 + (((pcol >> 3) ^ (prow & 7)) * 8) + (pcol & 7)] = f2bf(pp);
        rs[j] += pp;
      }
    }
#pragma unroll
    for (int j = 0; j < 4; ++j) {
      rs[j] += __shfl_xor(rs[j], 1);
      rs[j] += __shfl_xor(rs[j], 2);
      rs[j] += __shfl_xor(rs[j], 4);
      rs[j] += __shfl_xor(rs[j], 8);
      l_run[j] = l_run[j] * mx[j] + rs[j];
    }
#pragma unroll
    for (int nd = 0; nd < 4; ++nd)
#pragma unroll
      for (int j = 0; j < 4; ++j) oacc[nd][j] *= mx[j];

    __builtin_amdgcn_s_setprio(1);
#pragma unroll
    for (int kh = 0; kh < 2; ++kh) {
      bf16x8 pa = *(const bf16x8*)(Ps + (w * 16 + r) * 64
                                   + (((g + kh * 4) ^ (r & 7)) * 8));
#pragma unroll
      for (int nd = 0; nd < 4; ++nd) {
        bf16x8 vf = *(const bf16x8*)(Vt + (nd * 16 + r) * 64
                                     + (((g + kh * 4) ^ (r & 7)) * 8));
        oacc[nd] = __builtin_amdgcn_mfma_f32_16x16x32_bf16(pa, vf, oacc[nd], 0, 0, 0);
      }
    }
    __builtin_amdgcn_s_setprio(0);
  }

#pragma unroll
  for (int j = 0; j < 4; ++j) {
    float inv = 1.0f / l_run[j];
    int token = b * SQ + q0 + w * 16 + g * 4 + j;
#pragma unroll
    for (int nd = 0; nd < 4; ++nd)
      attnb[(size_t)token * HID + hh * DH + nd * 16 + r] = f2bf(oacc[nd][j] * inv);
  }
}

// ---------------------------------------------------------------------------
// Residual + LayerNorm + mask, bf16 residual stream.
// ---------------------------------------------------------------------------
__global__ __launch_bounds__(256) void ln_res_kernel(
    const ushort_t* __restrict__ t, const ushort_t* __restrict__ res,
    const float* __restrict__ g, const float* __restrict__ bb,
    const float* __restrict__ maskf, float* __restrict__ outf,
    ushort_t* __restrict__ outb)
{
  __shared__ float part[8];
  int row = blockIdx.x, tid = threadIdx.x;
  int wid = tid >> 6;
  const ushort_t* tp = t   + (size_t)row * HID;
  const ushort_t* rp = res + (size_t)row * HID;
  float y0 = bf2f(tp[tid      ]) + bf2f(rp[tid      ]);
  float y1 = bf2f(tp[tid + 256]) + bf2f(rp[tid + 256]);
  float y2 = bf2f(tp[tid + 512]) + bf2f(rp[tid + 512]);

  float s = y0 + y1 + y2;
  s += __shfl_xor(s, 1);  s += __shfl_xor(s, 2);  s += __shfl_xor(s, 4);
  s += __shfl_xor(s, 8);  s += __shfl_xor(s, 16); s += __shfl_xor(s, 32);
  if ((tid & 63) == 0) part[wid] = s;
  __syncthreads();
  float mu = (part[0] + part[1] + part[2] + part[3]) * (1.0f / 768.0f);

  float d0 = y0 - mu, d1 = y1 - mu, d2 = y2 - mu;
  float v = d0*d0 + d1*d1 + d2*d2;
  v += __shfl_xor(v, 1);  v += __shfl_xor(v, 2);  v += __shfl_xor(v, 4);
  v += __shfl_xor(v, 8);  v += __shfl_xor(v, 16); v += __shfl_xor(v, 32);
  if ((tid & 63) == 0) part[4 + wid] = v;
  __syncthreads();
  float rstd = rsqrtf((part[4] + part[5] + part[6] + part[7]) * (1.0f / 768.0f)
                      + 1e-12f);
  float mk = maskf[row];
  float v0 = (d0*rstd*g[tid      ] + bb[tid      ]) * mk;
  float v1 = (d1*rstd*g[tid + 256] + bb[tid + 256]) * mk;
  float v2 = (d2*rstd*g[tid + 512] + bb[tid + 512]) * mk;
  size_t base = (size_t)row * HID;
  outb[base + tid      ] = f2bf(v0);
  outb[base + tid + 256] = f2bf(v1);
  outb[base + tid + 512] = f2bf(v2);
  if (outf) {
    outf[base + tid      ] = v0;
    outf[base + tid + 256] = v1;
    outf[base + tid + 512] = v2;
  }
}

// ---------------------------------------------------------------------------
extern "C" void kernel_launch(void* const* d_in, const int* in_sizes, int n_in,
                              void* d_out, int out_size, void* d_ws, size_t ws_size,
                              hipStream_t stream) {
  const float* hidden     = (const float*)d_in[0];
  const float* amask      = (const float*)d_in[1];
  const float* Wqkv_w     = (const float*)d_in[2];
  const float* Wqkv_b     = (const float*)d_in[3];
  const float* attn_out_w = (const float*)d_in[4];
  const float* attn_out_b = (const float*)d_in[5];
  const float* ln1_g      = (const float*)d_in[6];
  const float* ln1_b      = (const float*)d_in[7];
  const float* glu_w      = (const float*)d_in[8];
  const float* wo_w       = (const float*)d_in[9];
  const float* wo_b       = (const float*)d_in[10];
  const float* ln2_g      = (const float*)d_in[11];
  const float* ln2_b      = (const float*)d_in[12];
  const float* r1         = (const float*)d_in[13];
  const float* r2         = (const float*)d_in[14];
  const float* r3         = (const float*)d_in[15];

  // workspace layout (floats first)
  float* ws       = (float*)d_ws;
  float* maskf    = ws;                           // 4096
  float* maskbias = maskf    + 4096;              // 4096
  float* kbt_all  = maskbias + 4096;              // NL*NH*SQ = 24576
  // ushorts
  ushort_t* us    = (ushort_t*)(kbt_all + NL*NH*SQ);
  ushort_t* hb    = us;                           // 3145728 (bf16 residual)
  ushort_t* aob   = hb    + (size_t)M_TOK*HID;    // 3145728 (bf16 residual)
  ushort_t* atnb  = aob   + (size_t)M_TOK*HID;    // 3145728
  ushort_t* tb    = atnb  + (size_t)M_TOK*HID;    // 3145728 (bf16 GEMM out)
  ushort_t* qkv_b = tb    + (size_t)M_TOK*HID;    // 9437184
  ushort_t* xb    = qkv_b + (size_t)M_TOK*3*HID;  // 12582912
  ushort_t* wbf   = xb    + (size_t)M_TOK*INTER;  // 9437184

  prep_kernel<<<(M_TOK*HID + 255)/256, 256, 0, stream>>>(
      hidden, amask, maskf, maskbias, hb);
  kerple_all_kernel<<<NL*NH, SQ, 0, stream>>>(r1, r2, r3, kbt_all);

  for (int l = 0; l < NL; ++l) {
    // ---- cast this layer's weights (one launch) ----
    wcast_layer_kernel<<<(WTOT/4 + 255)/256, 256, 0, stream>>>(
        Wqkv_w     + (size_t)l*WS0,
        attn_out_w + (size_t)l*WS1,
        glu_w      + (size_t)l*WS2,
        wo_w       + (size_t)l*WS3, wbf);
    ushort_t* wqkv = wbf;
    ushort_t* wao  = wbf + WS0;
    ushort_t* wga  = wbf + WS0 + WS1;
    ushort_t* wgb  = wga + (size_t)INTER*HID;
    ushort_t* wwo  = wbf + WS0 + WS1 + WS2;

    // ---- qkv_b = (hb @ Wqkv^T + b) * mask  [4096 x 2304] bf16 ----
    // MF=4 DB=1 (r11 config; r12's MF=2 doubled B staging -> -14us/layer)
    mfma_gemm<4,1,64,2,8,1,2><<<dim3(3*HID/128, M_TOK/128), 256, 0, stream>>>(
        hb, wqkv, nullptr, Wqkv_b + (size_t)l*3*HID, maskf, qkv_b, 3*HID, HID);

    // ---- attention -> atnb (bf16) ----
    attn_mfma<<<BQ*NH*8, 256, 0, stream>>>(
        qkv_b, kbt_all + (size_t)l*NH*SQ, maskbias, atnb);

    // ---- tb = attn @ attn_out_w^T + b  [4096 x 768] bf16 ----
    mfma_gemm<2,1,64,0,6,1,2><<<dim3(HID/128, M_TOK/64), 256, 0, stream>>>(
        atnb, wao, nullptr, attn_out_b + (size_t)l*HID, nullptr, tb, HID, HID);

    // ---- aob = LN(tb + hb) * mask  (bf16) ----
    ln_res_kernel<<<M_TOK, 256, 0, stream>>>(tb, hb, ln1_g + (size_t)l*HID,
                                             ln1_b + (size_t)l*HID, maskf,
                                             nullptr, aob);

    // ---- xb = gelu(aob @ Wa^T) * (aob @ Wb^T)  [4096 x 3072] bf16 ----
    // MF=2 NB=2 DB=0 WPB=4: 128-reg budget, LDS 40KB -> 4 blocks/CU target
    mfma_gemm<2,2,64,1,0,0,4><<<dim3(INTER/128, M_TOK/64), 256, 0, stream>>>(
        aob, wga, wgb, nullptr, nullptr, xb, INTER, HID);

    // ---- tb = x @ wo^T + wo_b  [4096 x 768] bf16 ----
    mfma_gemm<2,1,64,0,6,1,2><<<dim3(HID/128, M_TOK/64), 256, 0, stream>>>(
        xb, wwo, nullptr, wo_b + (size_t)l*HID, nullptr, tb, HID, INTER);

    // ---- hb = LN(tb + aob) * mask ; final layer also writes fp32 d_out ----
    float* hout = (l == NL - 1) ? (float*)d_out : nullptr;
    ln_res_kernel<<<M_TOK, 256, 0, stream>>>(tb, aob, ln2_g + (size_t)l*HID,
                                             ln2_b + (size_t)l*HID, maskf,
                                             hout, hb);
  }
}

// Round 14
// 738.076 us; speedup vs baseline: 1.0381x; 1.0381x over previous
//
#include <hip/hip_runtime.h>
#include <hip/hip_bf16.h>
#include <math.h>

// Problem dims
#define BQ 8
#define SQ 512
#define HID 768
#define NH 12
#define DH 64
#define INTER 3072
#define NL 4
#define M_TOK (BQ*SQ)   // 4096 tokens

typedef unsigned short ushort_t;
typedef __attribute__((ext_vector_type(8))) short bf16x8;
typedef __attribute__((ext_vector_type(8))) unsigned short u16x8;
typedef __attribute__((ext_vector_type(4))) float f32x4;

__device__ __forceinline__ float bf2f(ushort_t u) {
  union { float f; unsigned int i; } v; v.i = ((unsigned int)u) << 16; return v.f;
}
__device__ __forceinline__ ushort_t f2bf(float f) {
  __hip_bfloat16 h = __float2bfloat16(f);
  return *reinterpret_cast<ushort_t*>(&h);
}

__device__ __forceinline__ void gload_lds16(const ushort_t* g, ushort_t* l) {
  __builtin_amdgcn_global_load_lds(
      (const __attribute__((address_space(1))) void*)g,
      (__attribute__((address_space(3))) void*)l, 16, 0, 0);
}

template<int N>
__device__ __forceinline__ void wait_vm() {
  if constexpr (N == 0)      asm volatile("s_waitcnt vmcnt(0)" ::: "memory");
  else if constexpr (N == 6) asm volatile("s_waitcnt vmcnt(6)" ::: "memory");
  else if constexpr (N == 8) asm volatile("s_waitcnt vmcnt(8)" ::: "memory");
  else                       asm volatile("s_waitcnt vmcnt(12)" ::: "memory");
}

// ---------------------------------------------------------------------------
// prep: maskf, maskbias, hb = bf16(hidden*mask)
// ---------------------------------------------------------------------------
__global__ __launch_bounds__(256) void prep_kernel(
    const float* __restrict__ hidden, const float* __restrict__ amask,
    float* __restrict__ maskf, float* __restrict__ maskbias,
    ushort_t* __restrict__ hb)
{
  int i = blockIdx.x * 256 + threadIdx.x;
  if (i < M_TOK * HID) {
    float m = amask[i / HID];
    hb[i] = f2bf(hidden[i] * m);
    if (i < M_TOK) {
      maskf[i] = amask[i];
      maskbias[i] = (1.0f - amask[i]) * (-10000.0f);
    }
  }
}

// ---------------------------------------------------------------------------
// KERPLE bias tables for ALL layers: kbt_all[l][h][d]
// ---------------------------------------------------------------------------
__global__ void kerple_all_kernel(const float* __restrict__ r1,
                                  const float* __restrict__ r2,
                                  const float* __restrict__ r3,
                                  float* __restrict__ kbt_all)
{
  int lh = blockIdx.x;        // l*NH + h
  int d  = threadIdx.x;
  float c1 = fmaxf(r1[lh], 1e-7f);
  float c2 = fmaxf(r2[lh], 1e-7f);
  float c3 = fmaxf(r3[lh], 1e-7f);
  float v = 0.0f;
  if (d > 0) v = -c1 * log1pf(c2 * powf((float)d, c3));
  kbt_all[lh * SQ + d] = v;
}

// ---------------------------------------------------------------------------
// per-layer weight cast fp32 -> bf16, all 4 weight blocks in one launch.
// ---------------------------------------------------------------------------
#define WS0 (3*HID*HID)
#define WS1 (HID*HID)
#define WS2 (2*INTER*HID)
#define WS3 (HID*INTER)
#define WTOT (WS0+WS1+WS2+WS3)

__global__ __launch_bounds__(256) void wcast_layer_kernel(
    const float* __restrict__ w0, const float* __restrict__ w1,
    const float* __restrict__ w2, const float* __restrict__ w3,
    ushort_t* __restrict__ dst)
{
  int i = (blockIdx.x * 256 + threadIdx.x) * 4;
  if (i >= WTOT) return;
  const float* src; int off;
  if (i < WS0)                { src = w0; off = i; }
  else if (i < WS0+WS1)       { src = w1; off = i - WS0; }
  else if (i < WS0+WS1+WS2)   { src = w2; off = i - WS0 - WS1; }
  else                        { src = w3; off = i - WS0 - WS1 - WS2; }
  float4 v = *reinterpret_cast<const float4*>(src + off);
  ushort4 o;
  o.x = f2bf(v.x); o.y = f2bf(v.y); o.z = f2bf(v.z); o.w = f2bf(v.w);
  *reinterpret_cast<ushort4*>(dst + i) = o;
}

// ---------------------------------------------------------------------------
// bf16 MFMA GEMM. DB=1: counted-vmcnt double-buffer. DB=0: single-buffer.
// WPB = __launch_bounds__ min-waves-per-EU.
// Configs (measured): QKV MF=2 DB=1 (r12 best-run config); GLU MF=2 NB=2
// DB=0 WPB=4 (r13 per-dispatch best 66.5us); attn_out/wo MF=2 DB=1.
// Block decode: plain blockIdx (r10: linear dispatch already XCD-partitions bn).
// LDS XOR-swizzle at 16B-chunk granularity keyed on (row>>SSH)&SMK, both sides.
// ---------------------------------------------------------------------------
template<int MF, int NB, int BK, int EPI, int VN, int DB, int WPB>
__global__ __launch_bounds__(256, WPB) void mfma_gemm(
    const ushort_t* __restrict__ A, const ushort_t* __restrict__ B0p,
    const ushort_t* __restrict__ B1p, const float* __restrict__ bias,
    const float* __restrict__ rowscale, ushort_t* __restrict__ Cb,
    int N, int K)
{
  constexpr int BM   = MF * 32;
  constexpr int SMK  = BK / 8 - 1;            // swizzle mask (7 or 3)
  constexpr int SSH  = (BK == 32) ? 1 : 0;    // swizzle row shift
  constexpr int AIS  = (BM * BK * 2) / 4096;  // gload issues per wave, A tile
  constexpr int BIS  = (128 * BK * 2) / 4096; // per B tensor
  constexpr int KH   = BK / 32;
  constexpr int NBUF = DB ? 2 : 1;

  __shared__ ushort_t As_[NBUF][BM * BK];
  __shared__ ushort_t Bs_[NBUF][NB][128 * BK];

  int tid = threadIdx.x;
  int lane = tid & 63, w = tid >> 6;
  int wr = w >> 1, wc = w & 1;
  int g = lane >> 4, r = lane & 15;
  int bn = blockIdx.x, bm = blockIdx.y;

  f32x4 acc[NB][MF][4];
#pragma unroll
  for (int p = 0; p < NB; ++p)
#pragma unroll
    for (int m = 0; m < MF; ++m)
#pragma unroll
      for (int n = 0; n < 4; ++n) acc[p][m][n] = (f32x4){0.f, 0.f, 0.f, 0.f};

  const ushort_t* Arow  = A   + (size_t)bm * BM * K;
  const ushort_t* Brow0 = B0p + (size_t)bn * 128 * K;
  const ushort_t* Brow1 = (NB == 2) ? (B1p + (size_t)bn * 128 * K) : nullptr;

  auto stage = [&](const ushort_t* base, ushort_t* lds, int k0, int ISS_w) {
#pragma unroll
    for (int i = 0; i < 4; ++i) {
      if (i >= ISS_w) break;
      int o   = (w * ISS_w + i) * 1024 + lane * 16;  // byte offset in tile
      int row = o / (BK * 2);
      int pc  = (o >> 4) & SMK;
      int lc  = pc ^ ((row >> SSH) & SMK);
      gload_lds16(base + (size_t)row * K + k0 + lc * 8,
                  lds + ((w * ISS_w + i) << 9));
    }
  };
  auto stage_all = [&](int k0, int buf) {
    stage(Arow,  &As_[buf][0],    k0, AIS);
    stage(Brow0, &Bs_[buf][0][0], k0, BIS);
    if constexpr (NB == 2) stage(Brow1, &Bs_[buf][1][0], k0, BIS);
  };
  auto compute = [&](int buf) {
#pragma unroll
    for (int kh = 0; kh < KH; ++kh) {
      bf16x8 af[MF], bf_[4];
#pragma unroll
      for (int m = 0; m < MF; ++m)
        af[m] = *(const bf16x8*)(&As_[buf][(wr * (BM/2) + m * 16 + r) * BK
                  + (((kh * 4 + g) ^ ((r >> SSH) & SMK)) * 8)]);
#pragma unroll
      for (int n = 0; n < 4; ++n)
        bf_[n] = *(const bf16x8*)(&Bs_[buf][0][(wc * 64 + n * 16 + r) * BK
                  + (((kh * 4 + g) ^ ((r >> SSH) & SMK)) * 8)]);
#pragma unroll
      for (int m = 0; m < MF; ++m)
#pragma unroll
        for (int n = 0; n < 4; ++n)
          acc[0][m][n] = __builtin_amdgcn_mfma_f32_16x16x32_bf16(
              af[m], bf_[n], acc[0][m][n], 0, 0, 0);
      if constexpr (NB == 2) {
        bf16x8 bg[4];
#pragma unroll
        for (int n = 0; n < 4; ++n)
          bg[n] = *(const bf16x8*)(&Bs_[buf][1][(wc * 64 + n * 16 + r) * BK
                    + (((kh * 4 + g) ^ ((r >> SSH) & SMK)) * 8)]);
#pragma unroll
        for (int m = 0; m < MF; ++m)
#pragma unroll
          for (int n = 0; n < 4; ++n)
            acc[1][m][n] = __builtin_amdgcn_mfma_f32_16x16x32_bf16(
                af[m], bg[n], acc[1][m][n], 0, 0, 0);
      }
    }
  };

  int NT = K / BK;
  if constexpr (DB) {
    stage_all(0, 0);
    for (int t = 0; t < NT; ++t) {
      int cur = t & 1;
      if (t + 1 < NT) {
        stage_all((t + 1) * BK, cur ^ 1);
        wait_vm<VN>();             // current tile landed; next stays in flight
      } else {
        wait_vm<0>();
      }
      __builtin_amdgcn_s_barrier();
      compute(cur);
      __builtin_amdgcn_s_barrier(); // all reads of buf[cur] retired
    }
  } else {
    for (int t = 0; t < NT; ++t) {
      stage_all(t * BK, 0);
      wait_vm<0>();
      __builtin_amdgcn_s_barrier();
      compute(0);
      __builtin_amdgcn_s_barrier();
    }
  }

  // epilogue: C/D layout col=lane&15, row=(lane>>4)*4+j
  int r0 = bm * BM + wr * (BM/2), c0 = bn * 128 + wc * 64;
#pragma unroll
  for (int m = 0; m < MF; ++m)
#pragma unroll
    for (int n = 0; n < 4; ++n) {
      int col  = c0 + n * 16 + (lane & 15);
      int rowb = r0 + m * 16 + (lane >> 4) * 4;
      if constexpr (EPI == 0) {
        float bv = bias ? bias[col] : 0.0f;
#pragma unroll
        for (int j = 0; j < 4; ++j)
          Cb[(size_t)(rowb + j) * N + col] = f2bf(acc[0][m][n][j] + bv);
      } else if constexpr (EPI == 1) {
#pragma unroll
        for (int j = 0; j < 4; ++j) {
          float va = acc[0][m][n][j];
          float vb = acc[1][m][n][j];
          float ge = 0.5f * va * (1.0f + erff(va * 0.70710678118654752440f));
          Cb[(size_t)(rowb + j) * N + col] = f2bf(ge * vb);
        }
      } else {
        float bv = bias ? bias[col] : 0.0f;
#pragma unroll
        for (int j = 0; j < 4; ++j) {
          float v = (acc[0][m][n][j] + bv) * rowscale[rowb + j];
          Cb[(size_t)(rowb + j) * N + col] = f2bf(v);
        }
      }
    }
}

// ---------------------------------------------------------------------------
// MFMA flash attention, K/V double-buffered (T3/T14):
// per chunk: issue next-K gload_lds + next-V reg loads FIRST, compute
// QK^T/softmax/PV from current buffers (hides the load latency), then
// vmcnt(0) + write V regs->LDS + ONE barrier (was 2/iter).
// Race audit: buf i%2 holds chunk i; writes to buf[(i+1)%2] are issued only
// after the barrier that retired all reads of chunk i-1 from that buffer
// (__syncthreads waits lgkmcnt(0)). Ps is wave-private rows, no hazard.
// LDS 44KB -> 3 blocks/CU. T5 setprio + T1 XCD decode kept.
// ---------------------------------------------------------------------------
__global__ __launch_bounds__(256) void attn_mfma(
    const ushort_t* __restrict__ qkvb, const float* __restrict__ kbt,
    const float* __restrict__ maskbias, ushort_t* __restrict__ attnb)
{
  __shared__ ushort_t Ks[2][64 * 64];   // K[k][d], double-buffered
  __shared__ ushort_t Vt[2][64 * 64];   // V^T[d][k], double-buffered
  __shared__ ushort_t Ps[64 * 64];      // P[q][k] (wave-private rows)
  __shared__ float    kbs[SQ];
  __shared__ float    mbs[SQ];

  int tid  = threadIdx.x;
  int lane = tid & 63, w = tid >> 6;
  int g = lane >> 4, r = lane & 15;
  int bid = blockIdx.x;
  int qt = (bid >> 3) & 7;
  int t_ = (bid & 7) * 12 + (bid >> 6);
  int hh = t_ % NH;
  int b  = t_ / NH;
  int q0 = qt * 64;

  for (int i = tid; i < SQ; i += 256) {
    kbs[i] = kbt[hh * SQ + i];
    mbs[i] = maskbias[b * SQ + i];
  }

  bf16x8 qf[2];
  {
    const ushort_t* qsrc = qkvb + (size_t)(b * SQ + q0 + w * 16 + r) * (3 * HID)
                         + hh * DH + g * 8;
    qf[0] = *(const bf16x8*)(qsrc);
    qf[1] = *(const bf16x8*)(qsrc + 32);
  }

  float m_run[4], l_run[4];
  f32x4 oacc[4];
#pragma unroll
  for (int j = 0; j < 4; ++j) { m_run[j] = -1e30f; l_run[j] = 0.f; }
#pragma unroll
  for (int nd = 0; nd < 4; ++nd) oacc[nd] = (f32x4){0.f, 0.f, 0.f, 0.f};

  int k2 = (tid & 31) * 2, dg = tid >> 5;   // V staging assignment

  auto issue_K = [&](int kc, int buf) {
#pragma unroll
    for (int ii = 0; ii < 2; ++ii) {
      int row = (w * 2 + ii) * 8 + (lane >> 3);
      int c   = lane & 7;
      const ushort_t* src = qkvb + (size_t)(b * SQ + kc * 64 + row) * (3 * HID)
                          + HID + hh * DH + ((c ^ (row & 7)) * 8);
      gload_lds16(src, &Ks[buf][(w * 2 + ii) * 512 + lane * 8]);
    }
  };
  u16x8 va, vc;   // V regs in flight
  auto load_V = [&](int kc) {
    const ushort_t* v0 = qkvb + (size_t)(b * SQ + kc * 64 + k2) * (3 * HID)
                       + 2 * HID + hh * DH + dg * 8;
    va = *(const u16x8*)v0;
    vc = *(const u16x8*)(v0 + 3 * HID);
  };
  auto write_V = [&](int buf) {
#pragma unroll
    for (int u = 0; u < 8; ++u) {
      int d = dg * 8 + u;
      int addr = d * 64 + (((k2 >> 3) ^ (d & 7)) * 8) + (k2 & 7);
      ushort2 pr; pr.x = (ushort_t)va[u]; pr.y = (ushort_t)vc[u];
      *(ushort2*)(&Vt[buf][addr]) = pr;
    }
  };

  // prologue: stage chunk 0 into buf 0
  issue_K(0, 0);
  load_V(0);
  wait_vm<0>();
  write_V(0);
  __syncthreads();

  for (int kc = 0; kc < 8; ++kc) {
    int cur = kc & 1, nxt = cur ^ 1;
    if (kc + 1 < 8) {
      issue_K(kc + 1, nxt);     // stays in flight under this chunk's compute
      load_V(kc + 1);
    }

    f32x4 sacc[4];
#pragma unroll
    for (int n = 0; n < 4; ++n) sacc[n] = (f32x4){0.f, 0.f, 0.f, 0.f};
    __builtin_amdgcn_s_setprio(1);
#pragma unroll
    for (int kh = 0; kh < 2; ++kh) {
#pragma unroll
      for (int n = 0; n < 4; ++n) {
        bf16x8 kf = *(const bf16x8*)(&Ks[cur][(n * 16 + r) * 64
                                     + (((g + kh * 4) ^ (r & 7)) * 8)]);
        sacc[n] = __builtin_amdgcn_mfma_f32_16x16x32_bf16(qf[kh], kf, sacc[n], 0, 0, 0);
      }
    }
    __builtin_amdgcn_s_setprio(0);

    float sval[4][4], mx[4];
#pragma unroll
    for (int j = 0; j < 4; ++j) mx[j] = -1e30f;
#pragma unroll
    for (int n = 0; n < 4; ++n) {
      int kg = kc * 64 + n * 16 + r;
      float mb = mbs[kg];
#pragma unroll
      for (int j = 0; j < 4; ++j) {
        int qg = q0 + w * 16 + g * 4 + j;
        float s = sacc[n][j] * 0.125f + mb + kbs[abs(qg - kg)];
        sval[n][j] = s;
        mx[j] = fmaxf(mx[j], s);
      }
    }
#pragma unroll
    for (int j = 0; j < 4; ++j) {
      mx[j] = fmaxf(mx[j], __shfl_xor(mx[j], 1));
      mx[j] = fmaxf(mx[j], __shfl_xor(mx[j], 2));
      mx[j] = fmaxf(mx[j], __shfl_xor(mx[j], 4));
      mx[j] = fmaxf(mx[j], __shfl_xor(mx[j], 8));
      float mn = fmaxf(m_run[j], mx[j]);
      mx[j] = __expf(m_run[j] - mn);   // reuse as scale
      m_run[j] = mn;
    }
    float rs[4] = {0.f, 0.f, 0.f, 0.f};
#pragma unroll
    for (int n = 0; n < 4; ++n) {
#pragma unroll
      for (int j = 0; j < 4; ++j) {
        float pp = __expf(sval[n][j] - m_run[j]);
        int prow = w * 16 + g * 4 + j;
        int pcol = n * 16 + r;
        Ps[prow * 64 + (((pcol >> 3) ^ (prow & 7)) * 8) + (pcol & 7)] = f2bf(pp);
        rs[j] += pp;
      }
    }
#pragma unroll
    for (int j = 0; j < 4; ++j) {
      rs[j] += __shfl_xor(rs[j], 1);
      rs[j] += __shfl_xor(rs[j], 2);
      rs[j] += __shfl_xor(rs[j], 4);
      rs[j] += __shfl_xor(rs[j], 8);
      l_run[j] = l_run[j] * mx[j] + rs[j];
    }
#pragma unroll
    for (int nd = 0; nd < 4; ++nd)
#pragma unroll
      for (int j = 0; j < 4; ++j) oacc[nd][j] *= mx[j];

    __builtin_amdgcn_s_setprio(1);
#pragma unroll
    for (int kh = 0; kh < 2; ++kh) {
      bf16x8 pa = *(const bf16x8*)(Ps + (w * 16 + r) * 64
                                   + (((g + kh * 4) ^ (r & 7)) * 8));
#pragma unroll
      for (int nd = 0; nd < 4; ++nd) {
        bf16x8 vf = *(const bf16x8*)(&Vt[cur][(nd * 16 + r) * 64
                                     + (((g + kh * 4) ^ (r & 7)) * 8)]);
        oacc[nd] = __builtin_amdgcn_mfma_f32_16x16x32_bf16(pa, vf, oacc[nd], 0, 0, 0);
      }
    }
    __builtin_amdgcn_s_setprio(0);

    // finish staging chunk kc+1: drain loads (latency hidden by compute above)
    wait_vm<0>();
    if (kc + 1 < 8) write_V(nxt);
    __syncthreads();
  }

#pragma unroll
  for (int j = 0; j < 4; ++j) {
    float inv = 1.0f / l_run[j];
    int token = b * SQ + q0 + w * 16 + g * 4 + j;
#pragma unroll
    for (int nd = 0; nd < 4; ++nd)
      attnb[(size_t)token * HID + hh * DH + nd * 16 + r] = f2bf(oacc[nd][j] * inv);
  }
}

// ---------------------------------------------------------------------------
// Residual + LayerNorm + mask, bf16 residual stream.
// ---------------------------------------------------------------------------
__global__ __launch_bounds__(256) void ln_res_kernel(
    const ushort_t* __restrict__ t, const ushort_t* __restrict__ res,
    const float* __restrict__ g, const float* __restrict__ bb,
    const float* __restrict__ maskf, float* __restrict__ outf,
    ushort_t* __restrict__ outb)
{
  __shared__ float part[8];
  int row = blockIdx.x, tid = threadIdx.x;
  int wid = tid >> 6;
  const ushort_t* tp = t   + (size_t)row * HID;
  const ushort_t* rp = res + (size_t)row * HID;
  float y0 = bf2f(tp[tid      ]) + bf2f(rp[tid      ]);
  float y1 = bf2f(tp[tid + 256]) + bf2f(rp[tid + 256]);
  float y2 = bf2f(tp[tid + 512]) + bf2f(rp[tid + 512]);

  float s = y0 + y1 + y2;
  s += __shfl_xor(s, 1);  s += __shfl_xor(s, 2);  s += __shfl_xor(s, 4);
  s += __shfl_xor(s, 8);  s += __shfl_xor(s, 16); s += __shfl_xor(s, 32);
  if ((tid & 63) == 0) part[wid] = s;
  __syncthreads();
  float mu = (part[0] + part[1] + part[2] + part[3]) * (1.0f / 768.0f);

  float d0 = y0 - mu, d1 = y1 - mu, d2 = y2 - mu;
  float v = d0*d0 + d1*d1 + d2*d2;
  v += __shfl_xor(v, 1);  v += __shfl_xor(v, 2);  v += __shfl_xor(v, 4);
  v += __shfl_xor(v, 8);  v += __shfl_xor(v, 16); v += __shfl_xor(v, 32);
  if ((tid & 63) == 0) part[4 + wid] = v;
  __syncthreads();
  float rstd = rsqrtf((part[4] + part[5] + part[6] + part[7]) * (1.0f / 768.0f)
                      + 1e-12f);
  float mk = maskf[row];
  float v0 = (d0*rstd*g[tid      ] + bb[tid      ]) * mk;
  float v1 = (d1*rstd*g[tid + 256] + bb[tid + 256]) * mk;
  float v2 = (d2*rstd*g[tid + 512] + bb[tid + 512]) * mk;
  size_t base = (size_t)row * HID;
  outb[base + tid      ] = f2bf(v0);
  outb[base + tid + 256] = f2bf(v1);
  outb[base + tid + 512] = f2bf(v2);
  if (outf) {
    outf[base + tid      ] = v0;
    outf[base + tid + 256] = v1;
    outf[base + tid + 512] = v2;
  }
}

// ---------------------------------------------------------------------------
extern "C" void kernel_launch(void* const* d_in, const int* in_sizes, int n_in,
                              void* d_out, int out_size, void* d_ws, size_t ws_size,
                              hipStream_t stream) {
  const float* hidden     = (const float*)d_in[0];
  const float* amask      = (const float*)d_in[1];
  const float* Wqkv_w     = (const float*)d_in[2];
  const float* Wqkv_b     = (const float*)d_in[3];
  const float* attn_out_w = (const float*)d_in[4];
  const float* attn_out_b = (const float*)d_in[5];
  const float* ln1_g      = (const float*)d_in[6];
  const float* ln1_b      = (const float*)d_in[7];
  const float* glu_w      = (const float*)d_in[8];
  const float* wo_w       = (const float*)d_in[9];
  const float* wo_b       = (const float*)d_in[10];
  const float* ln2_g      = (const float*)d_in[11];
  const float* ln2_b      = (const float*)d_in[12];
  const float* r1         = (const float*)d_in[13];
  const float* r2         = (const float*)d_in[14];
  const float* r3         = (const float*)d_in[15];

  // workspace layout (floats first)
  float* ws       = (float*)d_ws;
  float* maskf    = ws;                           // 4096
  float* maskbias = maskf    + 4096;              // 4096
  float* kbt_all  = maskbias + 4096;              // NL*NH*SQ = 24576
  // ushorts
  ushort_t* us    = (ushort_t*)(kbt_all + NL*NH*SQ);
  ushort_t* hb    = us;                           // 3145728 (bf16 residual)
  ushort_t* aob   = hb    + (size_t)M_TOK*HID;    // 3145728 (bf16 residual)
  ushort_t* atnb  = aob   + (size_t)M_TOK*HID;    // 3145728
  ushort_t* tb    = atnb  + (size_t)M_TOK*HID;    // 3145728 (bf16 GEMM out)
  ushort_t* qkv_b = tb    + (size_t)M_TOK*HID;    // 9437184
  ushort_t* xb    = qkv_b + (size_t)M_TOK*3*HID;  // 12582912
  ushort_t* wbf   = xb    + (size_t)M_TOK*INTER;  // 9437184

  prep_kernel<<<(M_TOK*HID + 255)/256, 256, 0, stream>>>(
      hidden, amask, maskf, maskbias, hb);
  kerple_all_kernel<<<NL*NH, SQ, 0, stream>>>(r1, r2, r3, kbt_all);

  for (int l = 0; l < NL; ++l) {
    // ---- cast this layer's weights (one launch) ----
    wcast_layer_kernel<<<(WTOT/4 + 255)/256, 256, 0, stream>>>(
        Wqkv_w     + (size_t)l*WS0,
        attn_out_w + (size_t)l*WS1,
        glu_w      + (size_t)l*WS2,
        wo_w       + (size_t)l*WS3, wbf);
    ushort_t* wqkv = wbf;
    ushort_t* wao  = wbf + WS0;
    ushort_t* wga  = wbf + WS0 + WS1;
    ushort_t* wgb  = wga + (size_t)INTER*HID;
    ushort_t* wwo  = wbf + WS0 + WS1 + WS2;

    // ---- qkv_b = (hb @ Wqkv^T + b) * mask  [4096 x 2304] bf16 ----
    // MF=2 DB=1 (r12 best-run config; r13 subtraction confirms MF=2 better)
    mfma_gemm<2,1,64,2,6,1,2><<<dim3(3*HID/128, M_TOK/64), 256, 0, stream>>>(
        hb, wqkv, nullptr, Wqkv_b + (size_t)l*3*HID, maskf, qkv_b, 3*HID, HID);

    // ---- attention -> atnb (bf16), K/V double-buffered ----
    attn_mfma<<<BQ*NH*8, 256, 0, stream>>>(
        qkv_b, kbt_all + (size_t)l*NH*SQ, maskbias, atnb);

    // ---- tb = attn @ attn_out_w^T + b  [4096 x 768] bf16 ----
    mfma_gemm<2,1,64,0,6,1,2><<<dim3(HID/128, M_TOK/64), 256, 0, stream>>>(
        atnb, wao, nullptr, attn_out_b + (size_t)l*HID, nullptr, tb, HID, HID);

    // ---- aob = LN(tb + hb) * mask  (bf16) ----
    ln_res_kernel<<<M_TOK, 256, 0, stream>>>(tb, hb, ln1_g + (size_t)l*HID,
                                             ln1_b + (size_t)l*HID, maskf,
                                             nullptr, aob);

    // ---- xb = gelu(aob @ Wa^T) * (aob @ Wb^T)  [4096 x 3072] bf16 ----
    mfma_gemm<2,2,64,1,0,0,4><<<dim3(INTER/128, M_TOK/64), 256, 0, stream>>>(
        aob, wga, wgb, nullptr, nullptr, xb, INTER, HID);

    // ---- tb = x @ wo^T + wo_b  [4096 x 768] bf16 ----
    mfma_gemm<2,1,64,0,6,1,2><<<dim3(HID/128, M_TOK/64), 256, 0, stream>>>(
        xb, wwo, nullptr, wo_b + (size_t)l*HID, nullptr, tb, HID, INTER);

    // ---- hb = LN(tb + aob) * mask ; final layer also writes fp32 d_out ----
    float* hout = (l == NL - 1) ? (float*)d_out : nullptr;
    ln_res_kernel<<<M_TOK, 256, 0, stream>>>(tb, aob, ln2_g + (size_t)l*HID,
                                             ln2_b + (size_t)l*HID, maskf,
                                             hout, hb);
  }
}

// Round 15
// 733.614 us; speedup vs baseline: 1.0445x; 1.0061x over previous
//
#include <hip/hip_runtime.h>
#include <hip/hip_bf16.h>
#include <math.h>

// Problem dims
#define BQ 8
#define SQ 512
#define HID 768
#define NH 12
#define DH 64
#define INTER 3072
#define NL 4
#define M_TOK (BQ*SQ)   // 4096 tokens

typedef unsigned short ushort_t;
typedef __attribute__((ext_vector_type(8))) short bf16x8;
typedef __attribute__((ext_vector_type(8))) unsigned short u16x8;
typedef __attribute__((ext_vector_type(4))) float f32x4;

__device__ __forceinline__ float bf2f(ushort_t u) {
  union { float f; unsigned int i; } v; v.i = ((unsigned int)u) << 16; return v.f;
}
__device__ __forceinline__ ushort_t f2bf(float f) {
  __hip_bfloat16 h = __float2bfloat16(f);
  return *reinterpret_cast<ushort_t*>(&h);
}

__device__ __forceinline__ void gload_lds16(const ushort_t* g, ushort_t* l) {
  __builtin_amdgcn_global_load_lds(
      (const __attribute__((address_space(1))) void*)g,
      (__attribute__((address_space(3))) void*)l, 16, 0, 0);
}

template<int N>
__device__ __forceinline__ void wait_vm() {
  if constexpr (N == 0)      asm volatile("s_waitcnt vmcnt(0)" ::: "memory");
  else if constexpr (N == 5) asm volatile("s_waitcnt vmcnt(5)" ::: "memory");
  else if constexpr (N == 6) asm volatile("s_waitcnt vmcnt(6)" ::: "memory");
  else if constexpr (N == 8) asm volatile("s_waitcnt vmcnt(8)" ::: "memory");
  else                       asm volatile("s_waitcnt vmcnt(12)" ::: "memory");
}

// ---------------------------------------------------------------------------
// prep: maskf, maskbias, hb = bf16(hidden*mask)
// ---------------------------------------------------------------------------
__global__ __launch_bounds__(256) void prep_kernel(
    const float* __restrict__ hidden, const float* __restrict__ amask,
    float* __restrict__ maskf, float* __restrict__ maskbias,
    ushort_t* __restrict__ hb)
{
  int i = blockIdx.x * 256 + threadIdx.x;
  if (i < M_TOK * HID) {
    float m = amask[i / HID];
    hb[i] = f2bf(hidden[i] * m);
    if (i < M_TOK) {
      maskf[i] = amask[i];
      maskbias[i] = (1.0f - amask[i]) * (-10000.0f);
    }
  }
}

// ---------------------------------------------------------------------------
// KERPLE bias tables for ALL layers: kbt_all[l][h][d]
// ---------------------------------------------------------------------------
__global__ void kerple_all_kernel(const float* __restrict__ r1,
                                  const float* __restrict__ r2,
                                  const float* __restrict__ r3,
                                  float* __restrict__ kbt_all)
{
  int lh = blockIdx.x;        // l*NH + h
  int d  = threadIdx.x;
  float c1 = fmaxf(r1[lh], 1e-7f);
  float c2 = fmaxf(r2[lh], 1e-7f);
  float c3 = fmaxf(r3[lh], 1e-7f);
  float v = 0.0f;
  if (d > 0) v = -c1 * log1pf(c2 * powf((float)d, c3));
  kbt_all[lh * SQ + d] = v;
}

// ---------------------------------------------------------------------------
// per-layer weight cast fp32 -> bf16, all 4 weight blocks in one launch.
// ---------------------------------------------------------------------------
#define WS0 (3*HID*HID)
#define WS1 (HID*HID)
#define WS2 (2*INTER*HID)
#define WS3 (HID*INTER)
#define WTOT (WS0+WS1+WS2+WS3)

__global__ __launch_bounds__(256) void wcast_layer_kernel(
    const float* __restrict__ w0, const float* __restrict__ w1,
    const float* __restrict__ w2, const float* __restrict__ w3,
    ushort_t* __restrict__ dst)
{
  int i = (blockIdx.x * 256 + threadIdx.x) * 4;
  if (i >= WTOT) return;
  const float* src; int off;
  if (i < WS0)                { src = w0; off = i; }
  else if (i < WS0+WS1)       { src = w1; off = i - WS0; }
  else if (i < WS0+WS1+WS2)   { src = w2; off = i - WS0 - WS1; }
  else                        { src = w3; off = i - WS0 - WS1 - WS2; }
  float4 v = *reinterpret_cast<const float4*>(src + off);
  ushort4 o;
  o.x = f2bf(v.x); o.y = f2bf(v.y); o.z = f2bf(v.z); o.w = f2bf(v.w);
  *reinterpret_cast<ushort4*>(dst + i) = o;
}

// ---------------------------------------------------------------------------
// bf16 MFMA GEMM. DB=1: counted-vmcnt double-buffer. DB=0: single-buffer.
// WPB = __launch_bounds__ min-waves-per-EU.
// Configs (measured): QKV MF=2 DB=1 WPB=3; GLU MF=2 NB=2 DB=0 WPB=4;
// attn_out/wo MF=1 DB=1 WPB=3 (N=768 grids: MF=2 gave 384 blocks = 1.5/CU avg
// -> latency-hiding starved; MF=1 gives 768 = 3/CU exactly, acc 16 AGPR).
// Block decode: plain blockIdx (r10: linear dispatch already XCD-partitions bn).
// LDS XOR-swizzle at 16B-chunk granularity keyed on (row>>SSH)&SMK, both sides.
// ---------------------------------------------------------------------------
template<int MF, int NB, int BK, int EPI, int VN, int DB, int WPB>
__global__ __launch_bounds__(256, WPB) void mfma_gemm(
    const ushort_t* __restrict__ A, const ushort_t* __restrict__ B0p,
    const ushort_t* __restrict__ B1p, const float* __restrict__ bias,
    const float* __restrict__ rowscale, ushort_t* __restrict__ Cb,
    int N, int K)
{
  constexpr int BM   = MF * 32;
  constexpr int SMK  = BK / 8 - 1;            // swizzle mask (7 or 3)
  constexpr int SSH  = (BK == 32) ? 1 : 0;    // swizzle row shift
  constexpr int AIS  = (BM * BK * 2) / 4096;  // gload issues per wave, A tile
  constexpr int BIS  = (128 * BK * 2) / 4096; // per B tensor
  constexpr int KH   = BK / 32;
  constexpr int NBUF = DB ? 2 : 1;

  __shared__ ushort_t As_[NBUF][BM * BK];
  __shared__ ushort_t Bs_[NBUF][NB][128 * BK];

  int tid = threadIdx.x;
  int lane = tid & 63, w = tid >> 6;
  int wr = w >> 1, wc = w & 1;
  int g = lane >> 4, r = lane & 15;
  int bn = blockIdx.x, bm = blockIdx.y;

  f32x4 acc[NB][MF][4];
#pragma unroll
  for (int p = 0; p < NB; ++p)
#pragma unroll
    for (int m = 0; m < MF; ++m)
#pragma unroll
      for (int n = 0; n < 4; ++n) acc[p][m][n] = (f32x4){0.f, 0.f, 0.f, 0.f};

  const ushort_t* Arow  = A   + (size_t)bm * BM * K;
  const ushort_t* Brow0 = B0p + (size_t)bn * 128 * K;
  const ushort_t* Brow1 = (NB == 2) ? (B1p + (size_t)bn * 128 * K) : nullptr;

  auto stage = [&](const ushort_t* base, ushort_t* lds, int k0, int ISS_w) {
#pragma unroll
    for (int i = 0; i < 4; ++i) {
      if (i >= ISS_w) break;
      int o   = (w * ISS_w + i) * 1024 + lane * 16;  // byte offset in tile
      int row = o / (BK * 2);
      int pc  = (o >> 4) & SMK;
      int lc  = pc ^ ((row >> SSH) & SMK);
      gload_lds16(base + (size_t)row * K + k0 + lc * 8,
                  lds + ((w * ISS_w + i) << 9));
    }
  };
  auto stage_all = [&](int k0, int buf) {
    stage(Arow,  &As_[buf][0],    k0, AIS);
    stage(Brow0, &Bs_[buf][0][0], k0, BIS);
    if constexpr (NB == 2) stage(Brow1, &Bs_[buf][1][0], k0, BIS);
  };
  auto compute = [&](int buf) {
#pragma unroll
    for (int kh = 0; kh < KH; ++kh) {
      bf16x8 af[MF], bf_[4];
#pragma unroll
      for (int m = 0; m < MF; ++m)
        af[m] = *(const bf16x8*)(&As_[buf][(wr * (BM/2) + m * 16 + r) * BK
                  + (((kh * 4 + g) ^ ((r >> SSH) & SMK)) * 8)]);
#pragma unroll
      for (int n = 0; n < 4; ++n)
        bf_[n] = *(const bf16x8*)(&Bs_[buf][0][(wc * 64 + n * 16 + r) * BK
                  + (((kh * 4 + g) ^ ((r >> SSH) & SMK)) * 8)]);
#pragma unroll
      for (int m = 0; m < MF; ++m)
#pragma unroll
        for (int n = 0; n < 4; ++n)
          acc[0][m][n] = __builtin_amdgcn_mfma_f32_16x16x32_bf16(
              af[m], bf_[n], acc[0][m][n], 0, 0, 0);
      if constexpr (NB == 2) {
        bf16x8 bg[4];
#pragma unroll
        for (int n = 0; n < 4; ++n)
          bg[n] = *(const bf16x8*)(&Bs_[buf][1][(wc * 64 + n * 16 + r) * BK
                    + (((kh * 4 + g) ^ ((r >> SSH) & SMK)) * 8)]);
#pragma unroll
        for (int m = 0; m < MF; ++m)
#pragma unroll
          for (int n = 0; n < 4; ++n)
            acc[1][m][n] = __builtin_amdgcn_mfma_f32_16x16x32_bf16(
                af[m], bg[n], acc[1][m][n], 0, 0, 0);
      }
    }
  };

  int NT = K / BK;
  if constexpr (DB) {
    stage_all(0, 0);
    for (int t = 0; t < NT; ++t) {
      int cur = t & 1;
      if (t + 1 < NT) {
        stage_all((t + 1) * BK, cur ^ 1);
        wait_vm<VN>();             // current tile landed; next stays in flight
      } else {
        wait_vm<0>();
      }
      __builtin_amdgcn_s_barrier();
      compute(cur);
      __builtin_amdgcn_s_barrier(); // all reads of buf[cur] retired
    }
  } else {
    for (int t = 0; t < NT; ++t) {
      stage_all(t * BK, 0);
      wait_vm<0>();
      __builtin_amdgcn_s_barrier();
      compute(0);
      __builtin_amdgcn_s_barrier();
    }
  }

  // epilogue: C/D layout col=lane&15, row=(lane>>4)*4+j
  int r0 = bm * BM + wr * (BM/2), c0 = bn * 128 + wc * 64;
#pragma unroll
  for (int m = 0; m < MF; ++m)
#pragma unroll
    for (int n = 0; n < 4; ++n) {
      int col  = c0 + n * 16 + (lane & 15);
      int rowb = r0 + m * 16 + (lane >> 4) * 4;
      if constexpr (EPI == 0) {
        float bv = bias ? bias[col] : 0.0f;
#pragma unroll
        for (int j = 0; j < 4; ++j)
          Cb[(size_t)(rowb + j) * N + col] = f2bf(acc[0][m][n][j] + bv);
      } else if constexpr (EPI == 1) {
#pragma unroll
        for (int j = 0; j < 4; ++j) {
          float va = acc[0][m][n][j];
          float vb = acc[1][m][n][j];
          float ge = 0.5f * va * (1.0f + erff(va * 0.70710678118654752440f));
          Cb[(size_t)(rowb + j) * N + col] = f2bf(ge * vb);
        }
      } else {
        float bv = bias ? bias[col] : 0.0f;
#pragma unroll
        for (int j = 0; j < 4; ++j) {
          float v = (acc[0][m][n][j] + bv) * rowscale[rowb + j];
          Cb[(size_t)(rowb + j) * N + col] = f2bf(v);
        }
      }
    }
}

// ---------------------------------------------------------------------------
// MFMA flash attention, K/V double-buffered (r14-proven). T5 setprio + T1
// XCD decode kept.
// ---------------------------------------------------------------------------
__global__ __launch_bounds__(256) void attn_mfma(
    const ushort_t* __restrict__ qkvb, const float* __restrict__ kbt,
    const float* __restrict__ maskbias, ushort_t* __restrict__ attnb)
{
  __shared__ ushort_t Ks[2][64 * 64];   // K[k][d], double-buffered
  __shared__ ushort_t Vt[2][64 * 64];   // V^T[d][k], double-buffered
  __shared__ ushort_t Ps[64 * 64];      // P[q][k] (wave-private rows)
  __shared__ float    kbs[SQ];
  __shared__ float    mbs[SQ];

  int tid  = threadIdx.x;
  int lane = tid & 63, w = tid >> 6;
  int g = lane >> 4, r = lane & 15;
  int bid = blockIdx.x;
  int qt = (bid >> 3) & 7;
  int t_ = (bid & 7) * 12 + (bid >> 6);
  int hh = t_ % NH;
  int b  = t_ / NH;
  int q0 = qt * 64;

  for (int i = tid; i < SQ; i += 256) {
    kbs[i] = kbt[hh * SQ + i];
    mbs[i] = maskbias[b * SQ + i];
  }

  bf16x8 qf[2];
  {
    const ushort_t* qsrc = qkvb + (size_t)(b * SQ + q0 + w * 16 + r) * (3 * HID)
                         + hh * DH + g * 8;
    qf[0] = *(const bf16x8*)(qsrc);
    qf[1] = *(const bf16x8*)(qsrc + 32);
  }

  float m_run[4], l_run[4];
  f32x4 oacc[4];
#pragma unroll
  for (int j = 0; j < 4; ++j) { m_run[j] = -1e30f; l_run[j] = 0.f; }
#pragma unroll
  for (int nd = 0; nd < 4; ++nd) oacc[nd] = (f32x4){0.f, 0.f, 0.f, 0.f};

  int k2 = (tid & 31) * 2, dg = tid >> 5;   // V staging assignment

  auto issue_K = [&](int kc, int buf) {
#pragma unroll
    for (int ii = 0; ii < 2; ++ii) {
      int row = (w * 2 + ii) * 8 + (lane >> 3);
      int c   = lane & 7;
      const ushort_t* src = qkvb + (size_t)(b * SQ + kc * 64 + row) * (3 * HID)
                          + HID + hh * DH + ((c ^ (row & 7)) * 8);
      gload_lds16(src, &Ks[buf][(w * 2 + ii) * 512 + lane * 8]);
    }
  };
  u16x8 va, vc;   // V regs in flight
  auto load_V = [&](int kc) {
    const ushort_t* v0 = qkvb + (size_t)(b * SQ + kc * 64 + k2) * (3 * HID)
                       + 2 * HID + hh * DH + dg * 8;
    va = *(const u16x8*)v0;
    vc = *(const u16x8*)(v0 + 3 * HID);
  };
  auto write_V = [&](int buf) {
#pragma unroll
    for (int u = 0; u < 8; ++u) {
      int d = dg * 8 + u;
      int addr = d * 64 + (((k2 >> 3) ^ (d & 7)) * 8) + (k2 & 7);
      ushort2 pr; pr.x = (ushort_t)va[u]; pr.y = (ushort_t)vc[u];
      *(ushort2*)(&Vt[buf][addr]) = pr;
    }
  };

  // prologue: stage chunk 0 into buf 0
  issue_K(0, 0);
  load_V(0);
  wait_vm<0>();
  write_V(0);
  __syncthreads();

  for (int kc = 0; kc < 8; ++kc) {
    int cur = kc & 1, nxt = cur ^ 1;
    if (kc + 1 < 8) {
      issue_K(kc + 1, nxt);     // stays in flight under this chunk's compute
      load_V(kc + 1);
    }

    f32x4 sacc[4];
#pragma unroll
    for (int n = 0; n < 4; ++n) sacc[n] = (f32x4){0.f, 0.f, 0.f, 0.f};
    __builtin_amdgcn_s_setprio(1);
#pragma unroll
    for (int kh = 0; kh < 2; ++kh) {
#pragma unroll
      for (int n = 0; n < 4; ++n) {
        bf16x8 kf = *(const bf16x8*)(&Ks[cur][(n * 16 + r) * 64
                                     + (((g + kh * 4) ^ (r & 7)) * 8)]);
        sacc[n] = __builtin_amdgcn_mfma_f32_16x16x32_bf16(qf[kh], kf, sacc[n], 0, 0, 0);
      }
    }
    __builtin_amdgcn_s_setprio(0);

    float sval[4][4], mx[4];
#pragma unroll
    for (int j = 0; j < 4; ++j) mx[j] = -1e30f;
#pragma unroll
    for (int n = 0; n < 4; ++n) {
      int kg = kc * 64 + n * 16 + r;
      float mb = mbs[kg];
#pragma unroll
      for (int j = 0; j < 4; ++j) {
        int qg = q0 + w * 16 + g * 4 + j;
        float s = sacc[n][j] * 0.125f + mb + kbs[abs(qg - kg)];
        sval[n][j] = s;
        mx[j] = fmaxf(mx[j], s);
      }
    }
#pragma unroll
    for (int j = 0; j < 4; ++j) {
      mx[j] = fmaxf(mx[j], __shfl_xor(mx[j], 1));
      mx[j] = fmaxf(mx[j], __shfl_xor(mx[j], 2));
      mx[j] = fmaxf(mx[j], __shfl_xor(mx[j], 4));
      mx[j] = fmaxf(mx[j], __shfl_xor(mx[j], 8));
      float mn = fmaxf(m_run[j], mx[j]);
      mx[j] = __expf(m_run[j] - mn);   // reuse as scale
      m_run[j] = mn;
    }
    float rs[4] = {0.f, 0.f, 0.f, 0.f};
#pragma unroll
    for (int n = 0; n < 4; ++n) {
#pragma unroll
      for (int j = 0; j < 4; ++j) {
        float pp = __expf(sval[n][j] - m_run[j]);
        int prow = w * 16 + g * 4 + j;
        int pcol = n * 16 + r;
        Ps[prow * 64 + (((pcol >> 3) ^ (prow & 7)) * 8) + (pcol & 7)] = f2bf(pp);
        rs[j] += pp;
      }
    }
#pragma unroll
    for (int j = 0; j < 4; ++j) {
      rs[j] += __shfl_xor(rs[j], 1);
      rs[j] += __shfl_xor(rs[j], 2);
      rs[j] += __shfl_xor(rs[j], 4);
      rs[j] += __shfl_xor(rs[j], 8);
      l_run[j] = l_run[j] * mx[j] + rs[j];
    }
#pragma unroll
    for (int nd = 0; nd < 4; ++nd)
#pragma unroll
      for (int j = 0; j < 4; ++j) oacc[nd][j] *= mx[j];

    __builtin_amdgcn_s_setprio(1);
#pragma unroll
    for (int kh = 0; kh < 2; ++kh) {
      bf16x8 pa = *(const bf16x8*)(Ps + (w * 16 + r) * 64
                                   + (((g + kh * 4) ^ (r & 7)) * 8));
#pragma unroll
      for (int nd = 0; nd < 4; ++nd) {
        bf16x8 vf = *(const bf16x8*)(&Vt[cur][(nd * 16 + r) * 64
                                     + (((g + kh * 4) ^ (r & 7)) * 8)]);
        oacc[nd] = __builtin_amdgcn_mfma_f32_16x16x32_bf16(pa, vf, oacc[nd], 0, 0, 0);
      }
    }
    __builtin_amdgcn_s_setprio(0);

    // finish staging chunk kc+1: drain loads (latency hidden by compute above)
    wait_vm<0>();
    if (kc + 1 < 8) write_V(nxt);
    __syncthreads();
  }

#pragma unroll
  for (int j = 0; j < 4; ++j) {
    float inv = 1.0f / l_run[j];
    int token = b * SQ + q0 + w * 16 + g * 4 + j;
#pragma unroll
    for (int nd = 0; nd < 4; ++nd)
      attnb[(size_t)token * HID + hh * DH + nd * 16 + r] = f2bf(oacc[nd][j] * inv);
  }
}

// ---------------------------------------------------------------------------
// Residual + LayerNorm + mask, bf16 residual stream.
// ---------------------------------------------------------------------------
__global__ __launch_bounds__(256) void ln_res_kernel(
    const ushort_t* __restrict__ t, const ushort_t* __restrict__ res,
    const float* __restrict__ g, const float* __restrict__ bb,
    const float* __restrict__ maskf, float* __restrict__ outf,
    ushort_t* __restrict__ outb)
{
  __shared__ float part[8];
  int row = blockIdx.x, tid = threadIdx.x;
  int wid = tid >> 6;
  const ushort_t* tp = t   + (size_t)row * HID;
  const ushort_t* rp = res + (size_t)row * HID;
  float y0 = bf2f(tp[tid      ]) + bf2f(rp[tid      ]);
  float y1 = bf2f(tp[tid + 256]) + bf2f(rp[tid + 256]);
  float y2 = bf2f(tp[tid + 512]) + bf2f(rp[tid + 512]);

  float s = y0 + y1 + y2;
  s += __shfl_xor(s, 1);  s += __shfl_xor(s, 2);  s += __shfl_xor(s, 4);
  s += __shfl_xor(s, 8);  s += __shfl_xor(s, 16); s += __shfl_xor(s, 32);
  if ((tid & 63) == 0) part[wid] = s;
  __syncthreads();
  float mu = (part[0] + part[1] + part[2] + part[3]) * (1.0f / 768.0f);

  float d0 = y0 - mu, d1 = y1 - mu, d2 = y2 - mu;
  float v = d0*d0 + d1*d1 + d2*d2;
  v += __shfl_xor(v, 1);  v += __shfl_xor(v, 2);  v += __shfl_xor(v, 4);
  v += __shfl_xor(v, 8);  v += __shfl_xor(v, 16); v += __shfl_xor(v, 32);
  if ((tid & 63) == 0) part[4 + wid] = v;
  __syncthreads();
  float rstd = rsqrtf((part[4] + part[5] + part[6] + part[7]) * (1.0f / 768.0f)
                      + 1e-12f);
  float mk = maskf[row];
  float v0 = (d0*rstd*g[tid      ] + bb[tid      ]) * mk;
  float v1 = (d1*rstd*g[tid + 256] + bb[tid + 256]) * mk;
  float v2 = (d2*rstd*g[tid + 512] + bb[tid + 512]) * mk;
  size_t base = (size_t)row * HID;
  outb[base + tid      ] = f2bf(v0);
  outb[base + tid + 256] = f2bf(v1);
  outb[base + tid + 512] = f2bf(v2);
  if (outf) {
    outf[base + tid      ] = v0;
    outf[base + tid + 256] = v1;
    outf[base + tid + 512] = v2;
  }
}

// ---------------------------------------------------------------------------
extern "C" void kernel_launch(void* const* d_in, const int* in_sizes, int n_in,
                              void* d_out, int out_size, void* d_ws, size_t ws_size,
                              hipStream_t stream) {
  const float* hidden     = (const float*)d_in[0];
  const float* amask      = (const float*)d_in[1];
  const float* Wqkv_w     = (const float*)d_in[2];
  const float* Wqkv_b     = (const float*)d_in[3];
  const float* attn_out_w = (const float*)d_in[4];
  const float* attn_out_b = (const float*)d_in[5];
  const float* ln1_g      = (const float*)d_in[6];
  const float* ln1_b      = (const float*)d_in[7];
  const float* glu_w      = (const float*)d_in[8];
  const float* wo_w       = (const float*)d_in[9];
  const float* wo_b       = (const float*)d_in[10];
  const float* ln2_g      = (const float*)d_in[11];
  const float* ln2_b      = (const float*)d_in[12];
  const float* r1         = (const float*)d_in[13];
  const float* r2         = (const float*)d_in[14];
  const float* r3         = (const float*)d_in[15];

  // workspace layout (floats first)
  float* ws       = (float*)d_ws;
  float* maskf    = ws;                           // 4096
  float* maskbias = maskf    + 4096;              // 4096
  float* kbt_all  = maskbias + 4096;              // NL*NH*SQ = 24576
  // ushorts
  ushort_t* us    = (ushort_t*)(kbt_all + NL*NH*SQ);
  ushort_t* hb    = us;                           // 3145728 (bf16 residual)
  ushort_t* aob   = hb    + (size_t)M_TOK*HID;    // 3145728 (bf16 residual)
  ushort_t* atnb  = aob   + (size_t)M_TOK*HID;    // 3145728
  ushort_t* tb    = atnb  + (size_t)M_TOK*HID;    // 3145728 (bf16 GEMM out)
  ushort_t* qkv_b = tb    + (size_t)M_TOK*HID;    // 9437184
  ushort_t* xb    = qkv_b + (size_t)M_TOK*3*HID;  // 12582912
  ushort_t* wbf   = xb    + (size_t)M_TOK*INTER;  // 9437184

  prep_kernel<<<(M_TOK*HID + 255)/256, 256, 0, stream>>>(
      hidden, amask, maskf, maskbias, hb);
  kerple_all_kernel<<<NL*NH, SQ, 0, stream>>>(r1, r2, r3, kbt_all);

  for (int l = 0; l < NL; ++l) {
    // ---- cast this layer's weights (one launch) ----
    wcast_layer_kernel<<<(WTOT/4 + 255)/256, 256, 0, stream>>>(
        Wqkv_w     + (size_t)l*WS0,
        attn_out_w + (size_t)l*WS1,
        glu_w      + (size_t)l*WS2,
        wo_w       + (size_t)l*WS3, wbf);
    ushort_t* wqkv = wbf;
    ushort_t* wao  = wbf + WS0;
    ushort_t* wga  = wbf + WS0 + WS1;
    ushort_t* wgb  = wga + (size_t)INTER*HID;
    ushort_t* wwo  = wbf + WS0 + WS1 + WS2;

    // ---- qkv_b = (hb @ Wqkv^T + b) * mask  [4096 x 2304] bf16 ----
    mfma_gemm<2,1,64,2,6,1,3><<<dim3(3*HID/128, M_TOK/64), 256, 0, stream>>>(
        hb, wqkv, nullptr, Wqkv_b + (size_t)l*3*HID, maskf, qkv_b, 3*HID, HID);

    // ---- attention -> atnb (bf16), K/V double-buffered ----
    attn_mfma<<<BQ*NH*8, 256, 0, stream>>>(
        qkv_b, kbt_all + (size_t)l*NH*SQ, maskbias, atnb);

    // ---- tb = attn @ attn_out_w^T + b  [4096 x 768] bf16 ----
    // MF=1: grid (6,128)=768 blocks = 3/CU exactly (vs 384 = 1.5/CU at MF=2)
    mfma_gemm<1,1,64,0,5,1,3><<<dim3(HID/128, M_TOK/32), 256, 0, stream>>>(
        atnb, wao, nullptr, attn_out_b + (size_t)l*HID, nullptr, tb, HID, HID);

    // ---- aob = LN(tb + hb) * mask  (bf16) ----
    ln_res_kernel<<<M_TOK, 256, 0, stream>>>(tb, hb, ln1_g + (size_t)l*HID,
                                             ln1_b + (size_t)l*HID, maskf,
                                             nullptr, aob);

    // ---- xb = gelu(aob @ Wa^T) * (aob @ Wb^T)  [4096 x 3072] bf16 ----
    mfma_gemm<2,2,64,1,0,0,4><<<dim3(INTER/128, M_TOK/64), 256, 0, stream>>>(
        aob, wga, wgb, nullptr, nullptr, xb, INTER, HID);

    // ---- tb = x @ wo^T + wo_b  [4096 x 768] bf16 ----
    mfma_gemm<1,1,64,0,5,1,3><<<dim3(HID/128, M_TOK/32), 256, 0, stream>>>(
        xb, wwo, nullptr, wo_b + (size_t)l*HID, nullptr, tb, HID, INTER);

    // ---- hb = LN(tb + aob) * mask ; final layer also writes fp32 d_out ----
    float* hout = (l == NL - 1) ? (float*)d_out : nullptr;
    ln_res_kernel<<<M_TOK, 256, 0, stream>>>(tb, aob, ln2_g + (size_t)l*HID,
                                             ln2_b + (size_t)l*HID, maskf,
                                             hout, hb);
  }
}

// Round 16
// 725.015 us; speedup vs baseline: 1.0569x; 1.0119x over previous
//
#include <hip/hip_runtime.h>
#include <hip/hip_bf16.h>
#include <math.h>

// Problem dims
#define BQ 8
#define SQ 512
#define HID 768
#define NH 12
#define DH 64
#define INTER 3072
#define NL 4
#define M_TOK (BQ*SQ)   // 4096 tokens

typedef unsigned short ushort_t;
typedef __attribute__((ext_vector_type(8))) short bf16x8;
typedef __attribute__((ext_vector_type(8))) unsigned short u16x8;
typedef __attribute__((ext_vector_type(4))) float f32x4;

__device__ __forceinline__ float bf2f(ushort_t u) {
  union { float f; unsigned int i; } v; v.i = ((unsigned int)u) << 16; return v.f;
}
__device__ __forceinline__ ushort_t f2bf(float f) {
  __hip_bfloat16 h = __float2bfloat16(f);
  return *reinterpret_cast<ushort_t*>(&h);
}

__device__ __forceinline__ void gload_lds16(const ushort_t* g, ushort_t* l) {
  __builtin_amdgcn_global_load_lds(
      (const __attribute__((address_space(1))) void*)g,
      (__attribute__((address_space(3))) void*)l, 16, 0, 0);
}

template<int N>
__device__ __forceinline__ void wait_vm() {
  if constexpr (N == 0)      asm volatile("s_waitcnt vmcnt(0)" ::: "memory");
  else if constexpr (N == 5) asm volatile("s_waitcnt vmcnt(5)" ::: "memory");
  else if constexpr (N == 6) asm volatile("s_waitcnt vmcnt(6)" ::: "memory");
  else if constexpr (N == 8) asm volatile("s_waitcnt vmcnt(8)" ::: "memory");
  else                       asm volatile("s_waitcnt vmcnt(12)" ::: "memory");
}

// ---------------------------------------------------------------------------
// prep (vectorized): maskf, maskbias, hb = bf16(hidden*mask). 4 elems/thread;
// HID=768 is 4-divisible so a float4 never crosses a row.
// ---------------------------------------------------------------------------
__global__ __launch_bounds__(256) void prep_kernel(
    const float* __restrict__ hidden, const float* __restrict__ amask,
    float* __restrict__ maskf, float* __restrict__ maskbias,
    ushort_t* __restrict__ hb)
{
  int gid = blockIdx.x * 256 + threadIdx.x;
  int i = gid * 4;
  if (i < M_TOK * HID) {
    float m = amask[i / HID];
    float4 v = *reinterpret_cast<const float4*>(hidden + i);
    ushort4 o;
    o.x = f2bf(v.x * m); o.y = f2bf(v.y * m);
    o.z = f2bf(v.z * m); o.w = f2bf(v.w * m);
    *reinterpret_cast<ushort4*>(hb + i) = o;
  }
  if (gid < M_TOK) {
    float mv = amask[gid];
    maskf[gid] = mv;
    maskbias[gid] = (1.0f - mv) * (-10000.0f);
  }
}

// ---------------------------------------------------------------------------
// KERPLE bias tables for ALL layers: kbt_all[l][h][d]
// ---------------------------------------------------------------------------
__global__ void kerple_all_kernel(const float* __restrict__ r1,
                                  const float* __restrict__ r2,
                                  const float* __restrict__ r3,
                                  float* __restrict__ kbt_all)
{
  int lh = blockIdx.x;        // l*NH + h
  int d  = threadIdx.x;
  float c1 = fmaxf(r1[lh], 1e-7f);
  float c2 = fmaxf(r2[lh], 1e-7f);
  float c3 = fmaxf(r3[lh], 1e-7f);
  float v = 0.0f;
  if (d > 0) v = -c1 * log1pf(c2 * powf((float)d, c3));
  kbt_all[lh * SQ + d] = v;
}

// ---------------------------------------------------------------------------
// per-layer weight cast fp32 -> bf16, all 4 weight blocks in one launch.
// ---------------------------------------------------------------------------
#define WS0 (3*HID*HID)
#define WS1 (HID*HID)
#define WS2 (2*INTER*HID)
#define WS3 (HID*INTER)
#define WTOT (WS0+WS1+WS2+WS3)

__global__ __launch_bounds__(256) void wcast_layer_kernel(
    const float* __restrict__ w0, const float* __restrict__ w1,
    const float* __restrict__ w2, const float* __restrict__ w3,
    ushort_t* __restrict__ dst)
{
  int i = (blockIdx.x * 256 + threadIdx.x) * 4;
  if (i >= WTOT) return;
  const float* src; int off;
  if (i < WS0)                { src = w0; off = i; }
  else if (i < WS0+WS1)       { src = w1; off = i - WS0; }
  else if (i < WS0+WS1+WS2)   { src = w2; off = i - WS0 - WS1; }
  else                        { src = w3; off = i - WS0 - WS1 - WS2; }
  float4 v = *reinterpret_cast<const float4*>(src + off);
  ushort4 o;
  o.x = f2bf(v.x); o.y = f2bf(v.y); o.z = f2bf(v.z); o.w = f2bf(v.w);
  *reinterpret_cast<ushort4*>(dst + i) = o;
}

// ---------------------------------------------------------------------------
// bf16 MFMA GEMM (r15 proven configs, unchanged).
// QKV MF=2 DB=1 WPB=3; GLU MF=2 NB=2 DB=0 WPB=4; attn_out/wo MF=1 DB=1 WPB=3.
// LDS XOR-swizzle at 16B-chunk granularity keyed on (row>>SSH)&SMK, both sides.
// ---------------------------------------------------------------------------
template<int MF, int NB, int BK, int EPI, int VN, int DB, int WPB>
__global__ __launch_bounds__(256, WPB) void mfma_gemm(
    const ushort_t* __restrict__ A, const ushort_t* __restrict__ B0p,
    const ushort_t* __restrict__ B1p, const float* __restrict__ bias,
    const float* __restrict__ rowscale, ushort_t* __restrict__ Cb,
    int N, int K)
{
  constexpr int BM   = MF * 32;
  constexpr int SMK  = BK / 8 - 1;            // swizzle mask (7 or 3)
  constexpr int SSH  = (BK == 32) ? 1 : 0;    // swizzle row shift
  constexpr int AIS  = (BM * BK * 2) / 4096;  // gload issues per wave, A tile
  constexpr int BIS  = (128 * BK * 2) / 4096; // per B tensor
  constexpr int KH   = BK / 32;
  constexpr int NBUF = DB ? 2 : 1;

  __shared__ ushort_t As_[NBUF][BM * BK];
  __shared__ ushort_t Bs_[NBUF][NB][128 * BK];

  int tid = threadIdx.x;
  int lane = tid & 63, w = tid >> 6;
  int wr = w >> 1, wc = w & 1;
  int g = lane >> 4, r = lane & 15;
  int bn = blockIdx.x, bm = blockIdx.y;

  f32x4 acc[NB][MF][4];
#pragma unroll
  for (int p = 0; p < NB; ++p)
#pragma unroll
    for (int m = 0; m < MF; ++m)
#pragma unroll
      for (int n = 0; n < 4; ++n) acc[p][m][n] = (f32x4){0.f, 0.f, 0.f, 0.f};

  const ushort_t* Arow  = A   + (size_t)bm * BM * K;
  const ushort_t* Brow0 = B0p + (size_t)bn * 128 * K;
  const ushort_t* Brow1 = (NB == 2) ? (B1p + (size_t)bn * 128 * K) : nullptr;

  auto stage = [&](const ushort_t* base, ushort_t* lds, int k0, int ISS_w) {
#pragma unroll
    for (int i = 0; i < 4; ++i) {
      if (i >= ISS_w) break;
      int o   = (w * ISS_w + i) * 1024 + lane * 16;  // byte offset in tile
      int row = o / (BK * 2);
      int pc  = (o >> 4) & SMK;
      int lc  = pc ^ ((row >> SSH) & SMK);
      gload_lds16(base + (size_t)row * K + k0 + lc * 8,
                  lds + ((w * ISS_w + i) << 9));
    }
  };
  auto stage_all = [&](int k0, int buf) {
    stage(Arow,  &As_[buf][0],    k0, AIS);
    stage(Brow0, &Bs_[buf][0][0], k0, BIS);
    if constexpr (NB == 2) stage(Brow1, &Bs_[buf][1][0], k0, BIS);
  };
  auto compute = [&](int buf) {
#pragma unroll
    for (int kh = 0; kh < KH; ++kh) {
      bf16x8 af[MF], bf_[4];
#pragma unroll
      for (int m = 0; m < MF; ++m)
        af[m] = *(const bf16x8*)(&As_[buf][(wr * (BM/2) + m * 16 + r) * BK
                  + (((kh * 4 + g) ^ ((r >> SSH) & SMK)) * 8)]);
#pragma unroll
      for (int n = 0; n < 4; ++n)
        bf_[n] = *(const bf16x8*)(&Bs_[buf][0][(wc * 64 + n * 16 + r) * BK
                  + (((kh * 4 + g) ^ ((r >> SSH) & SMK)) * 8)]);
#pragma unroll
      for (int m = 0; m < MF; ++m)
#pragma unroll
        for (int n = 0; n < 4; ++n)
          acc[0][m][n] = __builtin_amdgcn_mfma_f32_16x16x32_bf16(
              af[m], bf_[n], acc[0][m][n], 0, 0, 0);
      if constexpr (NB == 2) {
        bf16x8 bg[4];
#pragma unroll
        for (int n = 0; n < 4; ++n)
          bg[n] = *(const bf16x8*)(&Bs_[buf][1][(wc * 64 + n * 16 + r) * BK
                    + (((kh * 4 + g) ^ ((r >> SSH) & SMK)) * 8)]);
#pragma unroll
        for (int m = 0; m < MF; ++m)
#pragma unroll
          for (int n = 0; n < 4; ++n)
            acc[1][m][n] = __builtin_amdgcn_mfma_f32_16x16x32_bf16(
                af[m], bg[n], acc[1][m][n], 0, 0, 0);
      }
    }
  };

  int NT = K / BK;
  if constexpr (DB) {
    stage_all(0, 0);
    for (int t = 0; t < NT; ++t) {
      int cur = t & 1;
      if (t + 1 < NT) {
        stage_all((t + 1) * BK, cur ^ 1);
        wait_vm<VN>();             // current tile landed; next stays in flight
      } else {
        wait_vm<0>();
      }
      __builtin_amdgcn_s_barrier();
      compute(cur);
      __builtin_amdgcn_s_barrier(); // all reads of buf[cur] retired
    }
  } else {
    for (int t = 0; t < NT; ++t) {
      stage_all(t * BK, 0);
      wait_vm<0>();
      __builtin_amdgcn_s_barrier();
      compute(0);
      __builtin_amdgcn_s_barrier();
    }
  }

  // epilogue: C/D layout col=lane&15, row=(lane>>4)*4+j
  int r0 = bm * BM + wr * (BM/2), c0 = bn * 128 + wc * 64;
#pragma unroll
  for (int m = 0; m < MF; ++m)
#pragma unroll
    for (int n = 0; n < 4; ++n) {
      int col  = c0 + n * 16 + (lane & 15);
      int rowb = r0 + m * 16 + (lane >> 4) * 4;
      if constexpr (EPI == 0) {
        float bv = bias ? bias[col] : 0.0f;
#pragma unroll
        for (int j = 0; j < 4; ++j)
          Cb[(size_t)(rowb + j) * N + col] = f2bf(acc[0][m][n][j] + bv);
      } else if constexpr (EPI == 1) {
#pragma unroll
        for (int j = 0; j < 4; ++j) {
          float va = acc[0][m][n][j];
          float vb = acc[1][m][n][j];
          float ge = 0.5f * va * (1.0f + erff(va * 0.70710678118654752440f));
          Cb[(size_t)(rowb + j) * N + col] = f2bf(ge * vb);
        }
      } else {
        float bv = bias ? bias[col] : 0.0f;
#pragma unroll
        for (int j = 0; j < 4; ++j) {
          float v = (acc[0][m][n][j] + bv) * rowscale[rowb + j];
          Cb[(size_t)(rowb + j) * N + col] = f2bf(v);
        }
      }
    }
}

// ---------------------------------------------------------------------------
// MFMA flash attention, K/V double-buffered (r14-proven). T5 setprio + T1
// XCD decode kept.
// ---------------------------------------------------------------------------
__global__ __launch_bounds__(256) void attn_mfma(
    const ushort_t* __restrict__ qkvb, const float* __restrict__ kbt,
    const float* __restrict__ maskbias, ushort_t* __restrict__ attnb)
{
  __shared__ ushort_t Ks[2][64 * 64];   // K[k][d], double-buffered
  __shared__ ushort_t Vt[2][64 * 64];   // V^T[d][k], double-buffered
  __shared__ ushort_t Ps[64 * 64];      // P[q][k] (wave-private rows)
  __shared__ float    kbs[SQ];
  __shared__ float    mbs[SQ];

  int tid  = threadIdx.x;
  int lane = tid & 63, w = tid >> 6;
  int g = lane >> 4, r = lane & 15;
  int bid = blockIdx.x;
  int qt = (bid >> 3) & 7;
  int t_ = (bid & 7) * 12 + (bid >> 6);
  int hh = t_ % NH;
  int b  = t_ / NH;
  int q0 = qt * 64;

  for (int i = tid; i < SQ; i += 256) {
    kbs[i] = kbt[hh * SQ + i];
    mbs[i] = maskbias[b * SQ + i];
  }

  bf16x8 qf[2];
  {
    const ushort_t* qsrc = qkvb + (size_t)(b * SQ + q0 + w * 16 + r) * (3 * HID)
                         + hh * DH + g * 8;
    qf[0] = *(const bf16x8*)(qsrc);
    qf[1] = *(const bf16x8*)(qsrc + 32);
  }

  float m_run[4], l_run[4];
  f32x4 oacc[4];
#pragma unroll
  for (int j = 0; j < 4; ++j) { m_run[j] = -1e30f; l_run[j] = 0.f; }
#pragma unroll
  for (int nd = 0; nd < 4; ++nd) oacc[nd] = (f32x4){0.f, 0.f, 0.f, 0.f};

  int k2 = (tid & 31) * 2, dg = tid >> 5;   // V staging assignment

  auto issue_K = [&](int kc, int buf) {
#pragma unroll
    for (int ii = 0; ii < 2; ++ii) {
      int row = (w * 2 + ii) * 8 + (lane >> 3);
      int c   = lane & 7;
      const ushort_t* src = qkvb + (size_t)(b * SQ + kc * 64 + row) * (3 * HID)
                          + HID + hh * DH + ((c ^ (row & 7)) * 8);
      gload_lds16(src, &Ks[buf][(w * 2 + ii) * 512 + lane * 8]);
    }
  };
  u16x8 va, vc;   // V regs in flight
  auto load_V = [&](int kc) {
    const ushort_t* v0 = qkvb + (size_t)(b * SQ + kc * 64 + k2) * (3 * HID)
                       + 2 * HID + hh * DH + dg * 8;
    va = *(const u16x8*)v0;
    vc = *(const u16x8*)(v0 + 3 * HID);
  };
  auto write_V = [&](int buf) {
#pragma unroll
    for (int u = 0; u < 8; ++u) {
      int d = dg * 8 + u;
      int addr = d * 64 + (((k2 >> 3) ^ (d & 7)) * 8) + (k2 & 7);
      ushort2 pr; pr.x = (ushort_t)va[u]; pr.y = (ushort_t)vc[u];
      *(ushort2*)(&Vt[buf][addr]) = pr;
    }
  };

  // prologue: stage chunk 0 into buf 0
  issue_K(0, 0);
  load_V(0);
  wait_vm<0>();
  write_V(0);
  __syncthreads();

  for (int kc = 0; kc < 8; ++kc) {
    int cur = kc & 1, nxt = cur ^ 1;
    if (kc + 1 < 8) {
      issue_K(kc + 1, nxt);     // stays in flight under this chunk's compute
      load_V(kc + 1);
    }

    f32x4 sacc[4];
#pragma unroll
    for (int n = 0; n < 4; ++n) sacc[n] = (f32x4){0.f, 0.f, 0.f, 0.f};
    __builtin_amdgcn_s_setprio(1);
#pragma unroll
    for (int kh = 0; kh < 2; ++kh) {
#pragma unroll
      for (int n = 0; n < 4; ++n) {
        bf16x8 kf = *(const bf16x8*)(&Ks[cur][(n * 16 + r) * 64
                                     + (((g + kh * 4) ^ (r & 7)) * 8)]);
        sacc[n] = __builtin_amdgcn_mfma_f32_16x16x32_bf16(qf[kh], kf, sacc[n], 0, 0, 0);
      }
    }
    __builtin_amdgcn_s_setprio(0);

    float sval[4][4], mx[4];
#pragma unroll
    for (int j = 0; j < 4; ++j) mx[j] = -1e30f;
#pragma unroll
    for (int n = 0; n < 4; ++n) {
      int kg = kc * 64 + n * 16 + r;
      float mb = mbs[kg];
#pragma unroll
      for (int j = 0; j < 4; ++j) {
        int qg = q0 + w * 16 + g * 4 + j;
        float s = sacc[n][j] * 0.125f + mb + kbs[abs(qg - kg)];
        sval[n][j] = s;
        mx[j] = fmaxf(mx[j], s);
      }
    }
#pragma unroll
    for (int j = 0; j < 4; ++j) {
      mx[j] = fmaxf(mx[j], __shfl_xor(mx[j], 1));
      mx[j] = fmaxf(mx[j], __shfl_xor(mx[j], 2));
      mx[j] = fmaxf(mx[j], __shfl_xor(mx[j], 4));
      mx[j] = fmaxf(mx[j], __shfl_xor(mx[j], 8));
      float mn = fmaxf(m_run[j], mx[j]);
      mx[j] = __expf(m_run[j] - mn);   // reuse as scale
      m_run[j] = mn;
    }
    float rs[4] = {0.f, 0.f, 0.f, 0.f};
#pragma unroll
    for (int n = 0; n < 4; ++n) {
#pragma unroll
      for (int j = 0; j < 4; ++j) {
        float pp = __expf(sval[n][j] - m_run[j]);
        int prow = w * 16 + g * 4 + j;
        int pcol = n * 16 + r;
        Ps[prow * 64 + (((pcol >> 3) ^ (prow & 7)) * 8) + (pcol & 7)] = f2bf(pp);
        rs[j] += pp;
      }
    }
#pragma unroll
    for (int j = 0; j < 4; ++j) {
      rs[j] += __shfl_xor(rs[j], 1);
      rs[j] += __shfl_xor(rs[j], 2);
      rs[j] += __shfl_xor(rs[j], 4);
      rs[j] += __shfl_xor(rs[j], 8);
      l_run[j] = l_run[j] * mx[j] + rs[j];
    }
#pragma unroll
    for (int nd = 0; nd < 4; ++nd)
#pragma unroll
      for (int j = 0; j < 4; ++j) oacc[nd][j] *= mx[j];

    __builtin_amdgcn_s_setprio(1);
#pragma unroll
    for (int kh = 0; kh < 2; ++kh) {
      bf16x8 pa = *(const bf16x8*)(Ps + (w * 16 + r) * 64
                                   + (((g + kh * 4) ^ (r & 7)) * 8));
#pragma unroll
      for (int nd = 0; nd < 4; ++nd) {
        bf16x8 vf = *(const bf16x8*)(&Vt[cur][(nd * 16 + r) * 64
                                     + (((g + kh * 4) ^ (r & 7)) * 8)]);
        oacc[nd] = __builtin_amdgcn_mfma_f32_16x16x32_bf16(pa, vf, oacc[nd], 0, 0, 0);
      }
    }
    __builtin_amdgcn_s_setprio(0);

    // finish staging chunk kc+1: drain loads (latency hidden by compute above)
    wait_vm<0>();
    if (kc + 1 < 8) write_V(nxt);
    __syncthreads();
  }

#pragma unroll
  for (int j = 0; j < 4; ++j) {
    float inv = 1.0f / l_run[j];
    int token = b * SQ + q0 + w * 16 + g * 4 + j;
#pragma unroll
    for (int nd = 0; nd < 4; ++nd)
      attnb[(size_t)token * HID + hh * DH + nd * 16 + r] = f2bf(oacc[nd][j] * inv);
  }
}

// ---------------------------------------------------------------------------
// Residual + LayerNorm + mask — one WAVE per row (4 rows/block), vectorized
// u16x8 + ushort4 loads (24 B/lane), pure shfl reduce: 0 LDS, 0 barriers.
// Lane layout: seg A = cols lane*8..lane*8+7 (0..511), seg B = 512+lane*4.
// ---------------------------------------------------------------------------
__global__ __launch_bounds__(256) void ln_res_kernel(
    const ushort_t* __restrict__ t, const ushort_t* __restrict__ res,
    const float* __restrict__ g, const float* __restrict__ bb,
    const float* __restrict__ maskf, float* __restrict__ outf,
    ushort_t* __restrict__ outb)
{
  int tid = threadIdx.x;
  int lane = tid & 63, wid = tid >> 6;
  int row = blockIdx.x * 4 + wid;
  size_t base = (size_t)row * HID;
  const ushort_t* tp = t   + base;
  const ushort_t* rp = res + base;
  int ca = lane * 8;           // segment A col
  int cbx = 512 + lane * 4;    // segment B col

  u16x8  ta = *(const u16x8*)(tp + ca);
  u16x8  ra = *(const u16x8*)(rp + ca);
  ushort4 tb4 = *(const ushort4*)(tp + cbx);
  ushort4 rb4 = *(const ushort4*)(rp + cbx);

  float y[12];
#pragma unroll
  for (int u = 0; u < 8; ++u)
    y[u] = bf2f((ushort_t)ta[u]) + bf2f((ushort_t)ra[u]);
  y[8]  = bf2f(tb4.x) + bf2f(rb4.x);
  y[9]  = bf2f(tb4.y) + bf2f(rb4.y);
  y[10] = bf2f(tb4.z) + bf2f(rb4.z);
  y[11] = bf2f(tb4.w) + bf2f(rb4.w);

  float s = 0.f;
#pragma unroll
  for (int u = 0; u < 12; ++u) s += y[u];
  s += __shfl_xor(s, 1);  s += __shfl_xor(s, 2);  s += __shfl_xor(s, 4);
  s += __shfl_xor(s, 8);  s += __shfl_xor(s, 16); s += __shfl_xor(s, 32);
  float mu = s * (1.0f / 768.0f);

  float v = 0.f;
#pragma unroll
  for (int u = 0; u < 12; ++u) { y[u] -= mu; v += y[u] * y[u]; }
  v += __shfl_xor(v, 1);  v += __shfl_xor(v, 2);  v += __shfl_xor(v, 4);
  v += __shfl_xor(v, 8);  v += __shfl_xor(v, 16); v += __shfl_xor(v, 32);
  float rstd = rsqrtf(v * (1.0f / 768.0f) + 1e-12f);
  float mk = maskf[row];

  float4 ga0 = *(const float4*)(g  + ca);
  float4 ga1 = *(const float4*)(g  + ca + 4);
  float4 ba0 = *(const float4*)(bb + ca);
  float4 ba1 = *(const float4*)(bb + ca + 4);
  float4 gB  = *(const float4*)(g  + cbx);
  float4 bB  = *(const float4*)(bb + cbx);

  float o[12];
  o[0]  = (y[0]*rstd*ga0.x + ba0.x) * mk;
  o[1]  = (y[1]*rstd*ga0.y + ba0.y) * mk;
  o[2]  = (y[2]*rstd*ga0.z + ba0.z) * mk;
  o[3]  = (y[3]*rstd*ga0.w + ba0.w) * mk;
  o[4]  = (y[4]*rstd*ga1.x + ba1.x) * mk;
  o[5]  = (y[5]*rstd*ga1.y + ba1.y) * mk;
  o[6]  = (y[6]*rstd*ga1.z + ba1.z) * mk;
  o[7]  = (y[7]*rstd*ga1.w + ba1.w) * mk;
  o[8]  = (y[8]*rstd*gB.x + bB.x) * mk;
  o[9]  = (y[9]*rstd*gB.y + bB.y) * mk;
  o[10] = (y[10]*rstd*gB.z + bB.z) * mk;
  o[11] = (y[11]*rstd*gB.w + bB.w) * mk;

  u16x8 oa;
#pragma unroll
  for (int u = 0; u < 8; ++u) oa[u] = f2bf(o[u]);
  *(u16x8*)(outb + base + ca) = oa;
  ushort4 ob4;
  ob4.x = f2bf(o[8]); ob4.y = f2bf(o[9]);
  ob4.z = f2bf(o[10]); ob4.w = f2bf(o[11]);
  *(ushort4*)(outb + base + cbx) = ob4;

  if (outf) {
    *(float4*)(outf + base + ca)     = (float4){o[0], o[1], o[2], o[3]};
    *(float4*)(outf + base + ca + 4) = (float4){o[4], o[5], o[6], o[7]};
    *(float4*)(outf + base + cbx)    = (float4){o[8], o[9], o[10], o[11]};
  }
}

// ---------------------------------------------------------------------------
extern "C" void kernel_launch(void* const* d_in, const int* in_sizes, int n_in,
                              void* d_out, int out_size, void* d_ws, size_t ws_size,
                              hipStream_t stream) {
  const float* hidden     = (const float*)d_in[0];
  const float* amask      = (const float*)d_in[1];
  const float* Wqkv_w     = (const float*)d_in[2];
  const float* Wqkv_b     = (const float*)d_in[3];
  const float* attn_out_w = (const float*)d_in[4];
  const float* attn_out_b = (const float*)d_in[5];
  const float* ln1_g      = (const float*)d_in[6];
  const float* ln1_b      = (const float*)d_in[7];
  const float* glu_w      = (const float*)d_in[8];
  const float* wo_w       = (const float*)d_in[9];
  const float* wo_b       = (const float*)d_in[10];
  const float* ln2_g      = (const float*)d_in[11];
  const float* ln2_b      = (const float*)d_in[12];
  const float* r1         = (const float*)d_in[13];
  const float* r2         = (const float*)d_in[14];
  const float* r3         = (const float*)d_in[15];

  // workspace layout (floats first)
  float* ws       = (float*)d_ws;
  float* maskf    = ws;                           // 4096
  float* maskbias = maskf    + 4096;              // 4096
  float* kbt_all  = maskbias + 4096;              // NL*NH*SQ = 24576
  // ushorts
  ushort_t* us    = (ushort_t*)(kbt_all + NL*NH*SQ);
  ushort_t* hb    = us;                           // 3145728 (bf16 residual)
  ushort_t* aob   = hb    + (size_t)M_TOK*HID;    // 3145728 (bf16 residual)
  ushort_t* atnb  = aob   + (size_t)M_TOK*HID;    // 3145728
  ushort_t* tb    = atnb  + (size_t)M_TOK*HID;    // 3145728 (bf16 GEMM out)
  ushort_t* qkv_b = tb    + (size_t)M_TOK*HID;    // 9437184
  ushort_t* xb    = qkv_b + (size_t)M_TOK*3*HID;  // 12582912
  ushort_t* wbf   = xb    + (size_t)M_TOK*INTER;  // 9437184

  prep_kernel<<<(M_TOK*HID/4 + 255)/256, 256, 0, stream>>>(
      hidden, amask, maskf, maskbias, hb);
  kerple_all_kernel<<<NL*NH, SQ, 0, stream>>>(r1, r2, r3, kbt_all);

  for (int l = 0; l < NL; ++l) {
    // ---- cast this layer's weights (one launch) ----
    wcast_layer_kernel<<<(WTOT/4 + 255)/256, 256, 0, stream>>>(
        Wqkv_w     + (size_t)l*WS0,
        attn_out_w + (size_t)l*WS1,
        glu_w      + (size_t)l*WS2,
        wo_w       + (size_t)l*WS3, wbf);
    ushort_t* wqkv = wbf;
    ushort_t* wao  = wbf + WS0;
    ushort_t* wga  = wbf + WS0 + WS1;
    ushort_t* wgb  = wga + (size_t)INTER*HID;
    ushort_t* wwo  = wbf + WS0 + WS1 + WS2;

    // ---- qkv_b = (hb @ Wqkv^T + b) * mask  [4096 x 2304] bf16 ----
    mfma_gemm<2,1,64,2,6,1,3><<<dim3(3*HID/128, M_TOK/64), 256, 0, stream>>>(
        hb, wqkv, nullptr, Wqkv_b + (size_t)l*3*HID, maskf, qkv_b, 3*HID, HID);

    // ---- attention -> atnb (bf16), K/V double-buffered ----
    attn_mfma<<<BQ*NH*8, 256, 0, stream>>>(
        qkv_b, kbt_all + (size_t)l*NH*SQ, maskbias, atnb);

    // ---- tb = attn @ attn_out_w^T + b  [4096 x 768] bf16 ----
    mfma_gemm<1,1,64,0,5,1,3><<<dim3(HID/128, M_TOK/32), 256, 0, stream>>>(
        atnb, wao, nullptr, attn_out_b + (size_t)l*HID, nullptr, tb, HID, HID);

    // ---- aob = LN(tb + hb) * mask  (bf16, wave-per-row) ----
    ln_res_kernel<<<M_TOK/4, 256, 0, stream>>>(tb, hb, ln1_g + (size_t)l*HID,
                                               ln1_b + (size_t)l*HID, maskf,
                                               nullptr, aob);

    // ---- xb = gelu(aob @ Wa^T) * (aob @ Wb^T)  [4096 x 3072] bf16 ----
    mfma_gemm<2,2,64,1,0,0,4><<<dim3(INTER/128, M_TOK/64), 256, 0, stream>>>(
        aob, wga, wgb, nullptr, nullptr, xb, INTER, HID);

    // ---- tb = x @ wo^T + wo_b  [4096 x 768] bf16 ----
    mfma_gemm<1,1,64,0,5,1,3><<<dim3(HID/128, M_TOK/32), 256, 0, stream>>>(
        xb, wwo, nullptr, wo_b + (size_t)l*HID, nullptr, tb, HID, INTER);

    // ---- hb = LN(tb + aob) * mask ; final layer also writes fp32 d_out ----
    float* hout = (l == NL - 1) ? (float*)d_out : nullptr;
    ln_res_kernel<<<M_TOK/4, 256, 0, stream>>>(tb, aob, ln2_g + (size_t)l*HID,
                                               ln2_b + (size_t)l*HID, maskf,
                                               hout, hb);
  }
}

// Round 17
// 707.504 us; speedup vs baseline: 1.0830x; 1.0248x over previous
//
#include <hip/hip_runtime.h>
#include <hip/hip_bf16.h>
#include <math.h>

// Problem dims
#define BQ 8
#define SQ 512
#define HID 768
#define NH 12
#define DH 64
#define INTER 3072
#define NL 4
#define M_TOK (BQ*SQ)   // 4096 tokens

typedef unsigned short ushort_t;
typedef __attribute__((ext_vector_type(8))) short bf16x8;
typedef __attribute__((ext_vector_type(8))) unsigned short u16x8;
typedef __attribute__((ext_vector_type(4))) float f32x4;

__device__ __forceinline__ float bf2f(ushort_t u) {
  union { float f; unsigned int i; } v; v.i = ((unsigned int)u) << 16; return v.f;
}
__device__ __forceinline__ ushort_t f2bf(float f) {
  __hip_bfloat16 h = __float2bfloat16(f);
  return *reinterpret_cast<ushort_t*>(&h);
}

__device__ __forceinline__ void gload_lds16(const ushort_t* g, ushort_t* l) {
  __builtin_amdgcn_global_load_lds(
      (const __attribute__((address_space(1))) void*)g,
      (__attribute__((address_space(3))) void*)l, 16, 0, 0);
}

template<int N>
__device__ __forceinline__ void wait_vm() {
  if constexpr (N == 0)      asm volatile("s_waitcnt vmcnt(0)" ::: "memory");
  else if constexpr (N == 5) asm volatile("s_waitcnt vmcnt(5)" ::: "memory");
  else if constexpr (N == 6) asm volatile("s_waitcnt vmcnt(6)" ::: "memory");
  else if constexpr (N == 8) asm volatile("s_waitcnt vmcnt(8)" ::: "memory");
  else                       asm volatile("s_waitcnt vmcnt(12)" ::: "memory");
}

// ---------------------------------------------------------------------------
// prep (vectorized)
// ---------------------------------------------------------------------------
__global__ __launch_bounds__(256) void prep_kernel(
    const float* __restrict__ hidden, const float* __restrict__ amask,
    float* __restrict__ maskf, float* __restrict__ maskbias,
    ushort_t* __restrict__ hb)
{
  int gid = blockIdx.x * 256 + threadIdx.x;
  int i = gid * 4;
  if (i < M_TOK * HID) {
    float m = amask[i / HID];
    float4 v = *reinterpret_cast<const float4*>(hidden + i);
    ushort4 o;
    o.x = f2bf(v.x * m); o.y = f2bf(v.y * m);
    o.z = f2bf(v.z * m); o.w = f2bf(v.w * m);
    *reinterpret_cast<ushort4*>(hb + i) = o;
  }
  if (gid < M_TOK) {
    float mv = amask[gid];
    maskf[gid] = mv;
    maskbias[gid] = (1.0f - mv) * (-10000.0f);
  }
}

// ---------------------------------------------------------------------------
// KERPLE bias tables for ALL layers
// ---------------------------------------------------------------------------
__global__ void kerple_all_kernel(const float* __restrict__ r1,
                                  const float* __restrict__ r2,
                                  const float* __restrict__ r3,
                                  float* __restrict__ kbt_all)
{
  int lh = blockIdx.x;
  int d  = threadIdx.x;
  float c1 = fmaxf(r1[lh], 1e-7f);
  float c2 = fmaxf(r2[lh], 1e-7f);
  float c3 = fmaxf(r3[lh], 1e-7f);
  float v = 0.0f;
  if (d > 0) v = -c1 * log1pf(c2 * powf((float)d, c3));
  kbt_all[lh * SQ + d] = v;
}

// ---------------------------------------------------------------------------
// per-layer weight cast fp32 -> bf16
// ---------------------------------------------------------------------------
#define WS0 (3*HID*HID)
#define WS1 (HID*HID)
#define WS2 (2*INTER*HID)
#define WS3 (HID*INTER)
#define WTOT (WS0+WS1+WS2+WS3)

__global__ __launch_bounds__(256) void wcast_layer_kernel(
    const float* __restrict__ w0, const float* __restrict__ w1,
    const float* __restrict__ w2, const float* __restrict__ w3,
    ushort_t* __restrict__ dst)
{
  int i = (blockIdx.x * 256 + threadIdx.x) * 4;
  if (i >= WTOT) return;
  const float* src; int off;
  if (i < WS0)                { src = w0; off = i; }
  else if (i < WS0+WS1)       { src = w1; off = i - WS0; }
  else if (i < WS0+WS1+WS2)   { src = w2; off = i - WS0 - WS1; }
  else                        { src = w3; off = i - WS0 - WS1 - WS2; }
  float4 v = *reinterpret_cast<const float4*>(src + off);
  ushort4 o;
  o.x = f2bf(v.x); o.y = f2bf(v.y); o.z = f2bf(v.z); o.w = f2bf(v.w);
  *reinterpret_cast<ushort4*>(dst + i) = o;
}

// ---------------------------------------------------------------------------
// bf16 MFMA GEMM.
// W14=1: 1x4 wave grid (each wave owns ALL BM rows x a 32-col slice) —
//   B operands read exactly once (vs 2x in 2x2 grid): per-kh LDS reads
//   40->32 KB for NB=2 (GLU) and 20->16 KB for MF=1 NB=1 (attn_out/wo).
//   QKV (MF=2 NB=1) is neutral -> stays 2x2 (W14=0).
// DB=1: counted-vmcnt double-buffer. DB=0: single-buffer.
// LDS XOR-swizzle at 16B-chunk granularity keyed on (row>>SSH)&SMK, both sides.
// ---------------------------------------------------------------------------
template<int MF, int NB, int BK, int EPI, int VN, int DB, int WPB, int W14>
__global__ __launch_bounds__(256, WPB) void mfma_gemm(
    const ushort_t* __restrict__ A, const ushort_t* __restrict__ B0p,
    const ushort_t* __restrict__ B1p, const float* __restrict__ bias,
    const float* __restrict__ rowscale, ushort_t* __restrict__ Cb,
    int N, int K)
{
  constexpr int BM   = MF * 32;
  constexpr int SMK  = BK / 8 - 1;
  constexpr int SSH  = (BK == 32) ? 1 : 0;
  constexpr int AIS  = (BM * BK * 2) / 4096;
  constexpr int BIS  = (128 * BK * 2) / 4096;
  constexpr int KH   = BK / 32;
  constexpr int NBUF = DB ? 2 : 1;
  constexpr int MPOS = W14 ? (BM / 16) : MF;   // m fragment positions / wave
  constexpr int NPOS = W14 ? 2 : 4;            // n fragment positions / wave

  __shared__ ushort_t As_[NBUF][BM * BK];
  __shared__ ushort_t Bs_[NBUF][NB][128 * BK];

  int tid = threadIdx.x;
  int lane = tid & 63, w = tid >> 6;
  int wr = w >> 1, wc = w & 1;
  int g = lane >> 4, r = lane & 15;
  int bn = blockIdx.x, bm = blockIdx.y;

  int rb0 = W14 ? 0 : wr * (BM / 2);   // per-wave row base
  int cb0 = W14 ? (w * 32) : (wc * 64);// per-wave col base

  f32x4 acc[NB][MPOS][NPOS];
#pragma unroll
  for (int p = 0; p < NB; ++p)
#pragma unroll
    for (int m = 0; m < MPOS; ++m)
#pragma unroll
      for (int n = 0; n < NPOS; ++n) acc[p][m][n] = (f32x4){0.f, 0.f, 0.f, 0.f};

  const ushort_t* Arow  = A   + (size_t)bm * BM * K;
  const ushort_t* Brow0 = B0p + (size_t)bn * 128 * K;
  const ushort_t* Brow1 = (NB == 2) ? (B1p + (size_t)bn * 128 * K) : nullptr;

  auto stage = [&](const ushort_t* base, ushort_t* lds, int k0, int ISS_w) {
#pragma unroll
    for (int i = 0; i < 4; ++i) {
      if (i >= ISS_w) break;
      int o   = (w * ISS_w + i) * 1024 + lane * 16;
      int row = o / (BK * 2);
      int pc  = (o >> 4) & SMK;
      int lc  = pc ^ ((row >> SSH) & SMK);
      gload_lds16(base + (size_t)row * K + k0 + lc * 8,
                  lds + ((w * ISS_w + i) << 9));
    }
  };
  auto stage_all = [&](int k0, int buf) {
    stage(Arow,  &As_[buf][0],    k0, AIS);
    stage(Brow0, &Bs_[buf][0][0], k0, BIS);
    if constexpr (NB == 2) stage(Brow1, &Bs_[buf][1][0], k0, BIS);
  };
  auto compute = [&](int buf) {
#pragma unroll
    for (int kh = 0; kh < KH; ++kh) {
      int kc = ((kh * 4 + g) ^ ((r >> SSH) & SMK)) * 8;
      bf16x8 af[MPOS], bf_[NPOS];
#pragma unroll
      for (int m = 0; m < MPOS; ++m)
        af[m] = *(const bf16x8*)(&As_[buf][(rb0 + m * 16 + r) * BK + kc]);
#pragma unroll
      for (int n = 0; n < NPOS; ++n)
        bf_[n] = *(const bf16x8*)(&Bs_[buf][0][(cb0 + n * 16 + r) * BK + kc]);
#pragma unroll
      for (int m = 0; m < MPOS; ++m)
#pragma unroll
        for (int n = 0; n < NPOS; ++n)
          acc[0][m][n] = __builtin_amdgcn_mfma_f32_16x16x32_bf16(
              af[m], bf_[n], acc[0][m][n], 0, 0, 0);
      if constexpr (NB == 2) {
        bf16x8 bg[NPOS];
#pragma unroll
        for (int n = 0; n < NPOS; ++n)
          bg[n] = *(const bf16x8*)(&Bs_[buf][1][(cb0 + n * 16 + r) * BK + kc]);
#pragma unroll
        for (int m = 0; m < MPOS; ++m)
#pragma unroll
          for (int n = 0; n < NPOS; ++n)
            acc[1][m][n] = __builtin_amdgcn_mfma_f32_16x16x32_bf16(
                af[m], bg[n], acc[1][m][n], 0, 0, 0);
      }
    }
  };

  int NT = K / BK;
  if constexpr (DB) {
    stage_all(0, 0);
    for (int t = 0; t < NT; ++t) {
      int cur = t & 1;
      if (t + 1 < NT) {
        stage_all((t + 1) * BK, cur ^ 1);
        wait_vm<VN>();
      } else {
        wait_vm<0>();
      }
      __builtin_amdgcn_s_barrier();
      compute(cur);
      __builtin_amdgcn_s_barrier();
    }
  } else {
    for (int t = 0; t < NT; ++t) {
      stage_all(t * BK, 0);
      wait_vm<0>();
      __builtin_amdgcn_s_barrier();
      compute(0);
      __builtin_amdgcn_s_barrier();
    }
  }

  // epilogue: C/D layout col=lane&15, row=(lane>>4)*4+j
  int r0 = bm * BM + rb0, c0 = bn * 128 + cb0;
#pragma unroll
  for (int m = 0; m < MPOS; ++m)
#pragma unroll
    for (int n = 0; n < NPOS; ++n) {
      int col  = c0 + n * 16 + (lane & 15);
      int rowb = r0 + m * 16 + (lane >> 4) * 4;
      if constexpr (EPI == 0) {
        float bv = bias ? bias[col] : 0.0f;
#pragma unroll
        for (int j = 0; j < 4; ++j)
          Cb[(size_t)(rowb + j) * N + col] = f2bf(acc[0][m][n][j] + bv);
      } else if constexpr (EPI == 1) {
#pragma unroll
        for (int j = 0; j < 4; ++j) {
          float va = acc[0][m][n][j];
          float vb = acc[1][m][n][j];
          float ge = 0.5f * va * (1.0f + erff(va * 0.70710678118654752440f));
          Cb[(size_t)(rowb + j) * N + col] = f2bf(ge * vb);
        }
      } else {
        float bv = bias ? bias[col] : 0.0f;
#pragma unroll
        for (int j = 0; j < 4; ++j) {
          float v = (acc[0][m][n][j] + bv) * rowscale[rowb + j];
          Cb[(size_t)(rowb + j) * N + col] = f2bf(v);
        }
      }
    }
}

// ---------------------------------------------------------------------------
// MFMA flash attention, K/V double-buffered (r14-proven).
// ---------------------------------------------------------------------------
__global__ __launch_bounds__(256) void attn_mfma(
    const ushort_t* __restrict__ qkvb, const float* __restrict__ kbt,
    const float* __restrict__ maskbias, ushort_t* __restrict__ attnb)
{
  __shared__ ushort_t Ks[2][64 * 64];
  __shared__ ushort_t Vt[2][64 * 64];
  __shared__ ushort_t Ps[64 * 64];
  __shared__ float    kbs[SQ];
  __shared__ float    mbs[SQ];

  int tid  = threadIdx.x;
  int lane = tid & 63, w = tid >> 6;
  int g = lane >> 4, r = lane & 15;
  int bid = blockIdx.x;
  int qt = (bid >> 3) & 7;
  int t_ = (bid & 7) * 12 + (bid >> 6);
  int hh = t_ % NH;
  int b  = t_ / NH;
  int q0 = qt * 64;

  for (int i = tid; i < SQ; i += 256) {
    kbs[i] = kbt[hh * SQ + i];
    mbs[i] = maskbias[b * SQ + i];
  }

  bf16x8 qf[2];
  {
    const ushort_t* qsrc = qkvb + (size_t)(b * SQ + q0 + w * 16 + r) * (3 * HID)
                         + hh * DH + g * 8;
    qf[0] = *(const bf16x8*)(qsrc);
    qf[1] = *(const bf16x8*)(qsrc + 32);
  }

  float m_run[4], l_run[4];
  f32x4 oacc[4];
#pragma unroll
  for (int j = 0; j < 4; ++j) { m_run[j] = -1e30f; l_run[j] = 0.f; }
#pragma unroll
  for (int nd = 0; nd < 4; ++nd) oacc[nd] = (f32x4){0.f, 0.f, 0.f, 0.f};

  int k2 = (tid & 31) * 2, dg = tid >> 5;

  auto issue_K = [&](int kc, int buf) {
#pragma unroll
    for (int ii = 0; ii < 2; ++ii) {
      int row = (w * 2 + ii) * 8 + (lane >> 3);
      int c   = lane & 7;
      const ushort_t* src = qkvb + (size_t)(b * SQ + kc * 64 + row) * (3 * HID)
                          + HID + hh * DH + ((c ^ (row & 7)) * 8);
      gload_lds16(src, &Ks[buf][(w * 2 + ii) * 512 + lane * 8]);
    }
  };
  u16x8 va, vc;
  auto load_V = [&](int kc) {
    const ushort_t* v0 = qkvb + (size_t)(b * SQ + kc * 64 + k2) * (3 * HID)
                       + 2 * HID + hh * DH + dg * 8;
    va = *(const u16x8*)v0;
    vc = *(const u16x8*)(v0 + 3 * HID);
  };
  auto write_V = [&](int buf) {
#pragma unroll
    for (int u = 0; u < 8; ++u) {
      int d = dg * 8 + u;
      int addr = d * 64 + (((k2 >> 3) ^ (d & 7)) * 8) + (k2 & 7);
      ushort2 pr; pr.x = (ushort_t)va[u]; pr.y = (ushort_t)vc[u];
      *(ushort2*)(&Vt[buf][addr]) = pr;
    }
  };

  issue_K(0, 0);
  load_V(0);
  wait_vm<0>();
  write_V(0);
  __syncthreads();

  for (int kc = 0; kc < 8; ++kc) {
    int cur = kc & 1, nxt = cur ^ 1;
    if (kc + 1 < 8) {
      issue_K(kc + 1, nxt);
      load_V(kc + 1);
    }

    f32x4 sacc[4];
#pragma unroll
    for (int n = 0; n < 4; ++n) sacc[n] = (f32x4){0.f, 0.f, 0.f, 0.f};
    __builtin_amdgcn_s_setprio(1);
#pragma unroll
    for (int kh = 0; kh < 2; ++kh) {
#pragma unroll
      for (int n = 0; n < 4; ++n) {
        bf16x8 kf = *(const bf16x8*)(&Ks[cur][(n * 16 + r) * 64
                                     + (((g + kh * 4) ^ (r & 7)) * 8)]);
        sacc[n] = __builtin_amdgcn_mfma_f32_16x16x32_bf16(qf[kh], kf, sacc[n], 0, 0, 0);
      }
    }
    __builtin_amdgcn_s_setprio(0);

    float sval[4][4], mx[4];
#pragma unroll
    for (int j = 0; j < 4; ++j) mx[j] = -1e30f;
#pragma unroll
    for (int n = 0; n < 4; ++n) {
      int kg = kc * 64 + n * 16 + r;
      float mb = mbs[kg];
#pragma unroll
      for (int j = 0; j < 4; ++j) {
        int qg = q0 + w * 16 + g * 4 + j;
        float s = sacc[n][j] * 0.125f + mb + kbs[abs(qg - kg)];
        sval[n][j] = s;
        mx[j] = fmaxf(mx[j], s);
      }
    }
#pragma unroll
    for (int j = 0; j < 4; ++j) {
      mx[j] = fmaxf(mx[j], __shfl_xor(mx[j], 1));
      mx[j] = fmaxf(mx[j], __shfl_xor(mx[j], 2));
      mx[j] = fmaxf(mx[j], __shfl_xor(mx[j], 4));
      mx[j] = fmaxf(mx[j], __shfl_xor(mx[j], 8));
      float mn = fmaxf(m_run[j], mx[j]);
      mx[j] = __expf(m_run[j] - mn);
      m_run[j] = mn;
    }
    float rs[4] = {0.f, 0.f, 0.f, 0.f};
#pragma unroll
    for (int n = 0; n < 4; ++n) {
#pragma unroll
      for (int j = 0; j < 4; ++j) {
        float pp = __expf(sval[n][j] - m_run[j]);
        int prow = w * 16 + g * 4 + j;
        int pcol = n * 16 + r;
        Ps[prow * 64 + (((pcol >> 3) ^ (prow & 7)) * 8) + (pcol & 7)] = f2bf(pp);
        rs[j] += pp;
      }
    }
#pragma unroll
    for (int j = 0; j < 4; ++j) {
      rs[j] += __shfl_xor(rs[j], 1);
      rs[j] += __shfl_xor(rs[j], 2);
      rs[j] += __shfl_xor(rs[j], 4);
      rs[j] += __shfl_xor(rs[j], 8);
      l_run[j] = l_run[j] * mx[j] + rs[j];
    }
#pragma unroll
    for (int nd = 0; nd < 4; ++nd)
#pragma unroll
      for (int j = 0; j < 4; ++j) oacc[nd][j] *= mx[j];

    __builtin_amdgcn_s_setprio(1);
#pragma unroll
    for (int kh = 0; kh < 2; ++kh) {
      bf16x8 pa = *(const bf16x8*)(Ps + (w * 16 + r) * 64
                                   + (((g + kh * 4) ^ (r & 7)) * 8));
#pragma unroll
      for (int nd = 0; nd < 4; ++nd) {
        bf16x8 vf = *(const bf16x8*)(&Vt[cur][(nd * 16 + r) * 64
                                     + (((g + kh * 4) ^ (r & 7)) * 8)]);
        oacc[nd] = __builtin_amdgcn_mfma_f32_16x16x32_bf16(pa, vf, oacc[nd], 0, 0, 0);
      }
    }
    __builtin_amdgcn_s_setprio(0);

    wait_vm<0>();
    if (kc + 1 < 8) write_V(nxt);
    __syncthreads();
  }

#pragma unroll
  for (int j = 0; j < 4; ++j) {
    float inv = 1.0f / l_run[j];
    int token = b * SQ + q0 + w * 16 + g * 4 + j;
#pragma unroll
    for (int nd = 0; nd < 4; ++nd)
      attnb[(size_t)token * HID + hh * DH + nd * 16 + r] = f2bf(oacc[nd][j] * inv);
  }
}

// ---------------------------------------------------------------------------
// Residual + LayerNorm + mask — wave-per-row, vectorized (r16-proven).
// ---------------------------------------------------------------------------
__global__ __launch_bounds__(256) void ln_res_kernel(
    const ushort_t* __restrict__ t, const ushort_t* __restrict__ res,
    const float* __restrict__ g, const float* __restrict__ bb,
    const float* __restrict__ maskf, float* __restrict__ outf,
    ushort_t* __restrict__ outb)
{
  int tid = threadIdx.x;
  int lane = tid & 63, wid = tid >> 6;
  int row = blockIdx.x * 4 + wid;
  size_t base = (size_t)row * HID;
  const ushort_t* tp = t   + base;
  const ushort_t* rp = res + base;
  int ca = lane * 8;
  int cbx = 512 + lane * 4;

  u16x8  ta = *(const u16x8*)(tp + ca);
  u16x8  ra = *(const u16x8*)(rp + ca);
  ushort4 tb4 = *(const ushort4*)(tp + cbx);
  ushort4 rb4 = *(const ushort4*)(rp + cbx);

  float y[12];
#pragma unroll
  for (int u = 0; u < 8; ++u)
    y[u] = bf2f((ushort_t)ta[u]) + bf2f((ushort_t)ra[u]);
  y[8]  = bf2f(tb4.x) + bf2f(rb4.x);
  y[9]  = bf2f(tb4.y) + bf2f(rb4.y);
  y[10] = bf2f(tb4.z) + bf2f(rb4.z);
  y[11] = bf2f(tb4.w) + bf2f(rb4.w);

  float s = 0.f;
#pragma unroll
  for (int u = 0; u < 12; ++u) s += y[u];
  s += __shfl_xor(s, 1);  s += __shfl_xor(s, 2);  s += __shfl_xor(s, 4);
  s += __shfl_xor(s, 8);  s += __shfl_xor(s, 16); s += __shfl_xor(s, 32);
  float mu = s * (1.0f / 768.0f);

  float v = 0.f;
#pragma unroll
  for (int u = 0; u < 12; ++u) { y[u] -= mu; v += y[u] * y[u]; }
  v += __shfl_xor(v, 1);  v += __shfl_xor(v, 2);  v += __shfl_xor(v, 4);
  v += __shfl_xor(v, 8);  v += __shfl_xor(v, 16); v += __shfl_xor(v, 32);
  float rstd = rsqrtf(v * (1.0f / 768.0f) + 1e-12f);
  float mk = maskf[row];

  float4 ga0 = *(const float4*)(g  + ca);
  float4 ga1 = *(const float4*)(g  + ca + 4);
  float4 ba0 = *(const float4*)(bb + ca);
  float4 ba1 = *(const float4*)(bb + ca + 4);
  float4 gB  = *(const float4*)(g  + cbx);
  float4 bB  = *(const float4*)(bb + cbx);

  float o[12];
  o[0]  = (y[0]*rstd*ga0.x + ba0.x) * mk;
  o[1]  = (y[1]*rstd*ga0.y + ba0.y) * mk;
  o[2]  = (y[2]*rstd*ga0.z + ba0.z) * mk;
  o[3]  = (y[3]*rstd*ga0.w + ba0.w) * mk;
  o[4]  = (y[4]*rstd*ga1.x + ba1.x) * mk;
  o[5]  = (y[5]*rstd*ga1.y + ba1.y) * mk;
  o[6]  = (y[6]*rstd*ga1.z + ba1.z) * mk;
  o[7]  = (y[7]*rstd*ga1.w + ba1.w) * mk;
  o[8]  = (y[8]*rstd*gB.x + bB.x) * mk;
  o[9]  = (y[9]*rstd*gB.y + bB.y) * mk;
  o[10] = (y[10]*rstd*gB.z + bB.z) * mk;
  o[11] = (y[11]*rstd*gB.w + bB.w) * mk;

  u16x8 oa;
#pragma unroll
  for (int u = 0; u < 8; ++u) oa[u] = f2bf(o[u]);
  *(u16x8*)(outb + base + ca) = oa;
  ushort4 ob4;
  ob4.x = f2bf(o[8]); ob4.y = f2bf(o[9]);
  ob4.z = f2bf(o[10]); ob4.w = f2bf(o[11]);
  *(ushort4*)(outb + base + cbx) = ob4;

  if (outf) {
    *(float4*)(outf + base + ca)     = (float4){o[0], o[1], o[2], o[3]};
    *(float4*)(outf + base + ca + 4) = (float4){o[4], o[5], o[6], o[7]};
    *(float4*)(outf + base + cbx)    = (float4){o[8], o[9], o[10], o[11]};
  }
}

// ---------------------------------------------------------------------------
extern "C" void kernel_launch(void* const* d_in, const int* in_sizes, int n_in,
                              void* d_out, int out_size, void* d_ws, size_t ws_size,
                              hipStream_t stream) {
  const float* hidden     = (const float*)d_in[0];
  const float* amask      = (const float*)d_in[1];
  const float* Wqkv_w     = (const float*)d_in[2];
  const float* Wqkv_b     = (const float*)d_in[3];
  const float* attn_out_w = (const float*)d_in[4];
  const float* attn_out_b = (const float*)d_in[5];
  const float* ln1_g      = (const float*)d_in[6];
  const float* ln1_b      = (const float*)d_in[7];
  const float* glu_w      = (const float*)d_in[8];
  const float* wo_w       = (const float*)d_in[9];
  const float* wo_b       = (const float*)d_in[10];
  const float* ln2_g      = (const float*)d_in[11];
  const float* ln2_b      = (const float*)d_in[12];
  const float* r1         = (const float*)d_in[13];
  const float* r2         = (const float*)d_in[14];
  const float* r3         = (const float*)d_in[15];

  // workspace layout (floats first)
  float* ws       = (float*)d_ws;
  float* maskf    = ws;                           // 4096
  float* maskbias = maskf    + 4096;              // 4096
  float* kbt_all  = maskbias + 4096;              // NL*NH*SQ = 24576
  // ushorts
  ushort_t* us    = (ushort_t*)(kbt_all + NL*NH*SQ);
  ushort_t* hb    = us;                           // 3145728 (bf16 residual)
  ushort_t* aob   = hb    + (size_t)M_TOK*HID;    // 3145728 (bf16 residual)
  ushort_t* atnb  = aob   + (size_t)M_TOK*HID;    // 3145728
  ushort_t* tb    = atnb  + (size_t)M_TOK*HID;    // 3145728 (bf16 GEMM out)
  ushort_t* qkv_b = tb    + (size_t)M_TOK*HID;    // 9437184
  ushort_t* xb    = qkv_b + (size_t)M_TOK*3*HID;  // 12582912
  ushort_t* wbf   = xb    + (size_t)M_TOK*INTER;  // 9437184

  prep_kernel<<<(M_TOK*HID/4 + 255)/256, 256, 0, stream>>>(
      hidden, amask, maskf, maskbias, hb);
  kerple_all_kernel<<<NL*NH, SQ, 0, stream>>>(r1, r2, r3, kbt_all);

  for (int l = 0; l < NL; ++l) {
    // ---- cast this layer's weights (one launch) ----
    wcast_layer_kernel<<<(WTOT/4 + 255)/256, 256, 0, stream>>>(
        Wqkv_w     + (size_t)l*WS0,
        attn_out_w + (size_t)l*WS1,
        glu_w      + (size_t)l*WS2,
        wo_w       + (size_t)l*WS3, wbf);
    ushort_t* wqkv = wbf;
    ushort_t* wao  = wbf + WS0;
    ushort_t* wga  = wbf + WS0 + WS1;
    ushort_t* wgb  = wga + (size_t)INTER*HID;
    ushort_t* wwo  = wbf + WS0 + WS1 + WS2;

    // ---- qkv_b = (hb @ Wqkv^T + b) * mask  [4096 x 2304] bf16 ----
    mfma_gemm<2,1,64,2,6,1,3,0><<<dim3(3*HID/128, M_TOK/64), 256, 0, stream>>>(
        hb, wqkv, nullptr, Wqkv_b + (size_t)l*3*HID, maskf, qkv_b, 3*HID, HID);

    // ---- attention -> atnb (bf16), K/V double-buffered ----
    attn_mfma<<<BQ*NH*8, 256, 0, stream>>>(
        qkv_b, kbt_all + (size_t)l*NH*SQ, maskbias, atnb);

    // ---- tb = attn @ attn_out_w^T + b  [4096 x 768] bf16, W14 wave grid ----
    mfma_gemm<1,1,64,0,5,1,4,1><<<dim3(HID/128, M_TOK/32), 256, 0, stream>>>(
        atnb, wao, nullptr, attn_out_b + (size_t)l*HID, nullptr, tb, HID, HID);

    // ---- aob = LN(tb + hb) * mask ----
    ln_res_kernel<<<M_TOK/4, 256, 0, stream>>>(tb, hb, ln1_g + (size_t)l*HID,
                                               ln1_b + (size_t)l*HID, maskf,
                                               nullptr, aob);

    // ---- xb = gelu(aob @ Wa^T) * (aob @ Wb^T)  [4096 x 3072] bf16, W14 ----
    mfma_gemm<2,2,64,1,0,0,4,1><<<dim3(INTER/128, M_TOK/64), 256, 0, stream>>>(
        aob, wga, wgb, nullptr, nullptr, xb, INTER, HID);

    // ---- tb = x @ wo^T + wo_b  [4096 x 768] bf16, W14 wave grid ----
    mfma_gemm<1,1,64,0,5,1,4,1><<<dim3(HID/128, M_TOK/32), 256, 0, stream>>>(
        xb, wwo, nullptr, wo_b + (size_t)l*HID, nullptr, tb, HID, INTER);

    // ---- hb = LN(tb + aob) * mask ; final layer also writes fp32 d_out ----
    float* hout = (l == NL - 1) ? (float*)d_out : nullptr;
    ln_res_kernel<<<M_TOK/4, 256, 0, stream>>>(tb, aob, ln2_g + (size_t)l*HID,
                                               ln2_b + (size_t)l*HID, maskf,
                                               hout, hb);
  }
}